// Round 7
// baseline (2330.098 us; speedup 1.0000x reference)
//
#include <hip/hip_runtime.h>

#define NB 8
#define NPTS 16384
#define S 1024
#define KNEI 32
#define MROWS (NB*S*KNEI)   // 262144

typedef float v2f __attribute__((ext_vector_type(2)));

// u64 key max combine via DPP halves, bound_ctrl=1 (identity 0 always loses:
// every real key >= 1 because of the 16384-idx field).
#define DPP_MAXK0(CTRL, k) do {                                               \
    int _olo = __builtin_amdgcn_update_dpp(0, (int)(unsigned)(k),             \
                                           (CTRL), 0xF, 0xF, true);           \
    int _ohi = __builtin_amdgcn_update_dpp(0, (int)(unsigned)((k) >> 32),     \
                                           (CTRL), 0xF, 0xF, true);           \
    unsigned long long _ok = (((unsigned long long)(unsigned)_ohi) << 32)     \
                           | (unsigned)_olo;                                  \
    if (_ok > (k)) (k) = _ok;                                                 \
  } while (0)

#define DPP_ROW_SHR1   0x111
#define DPP_ROW_SHR2   0x112
#define DPP_ROW_SHR4   0x114
#define DPP_ROW_SHR8   0x118
#define DPP_ROW_BCAST15 0x142
#define DPP_ROW_BCAST31 0x143

// ---------------------------------------------------------------------------
// FPS r15 (resubmit -- r6 bench was an infra failure, kernel unchanged):
// r14 (box-skip) measured 3104 cyc/step at ~55% issue / 45% latency.
// This round collapses the per-step reduce:
//  * perm_reg[8] (u16 pairs) keeps orig indices REGISTER-resident -> locate
//    needs no LDS; active lanes recompute (ub, mi) in-pass; inactive lanes
//    reuse cached values (dist[] unchanged => (ub,mi) still exact).
//  * ONE u64 DPP chain per wave: key = dist_bits<<15 | (16384-mi)
//    == lexicographic (max dist, min orig idx) -- identical tie-break
//    (numpy first-occurrence) to r12/r14's two-chain version.
//  * wave-inactive fast path: ballot(active)==0 -> skip chain, winner lane
//    and key cached from the last active step (provably unchanged).
//  * winner lane publishes key AND coords (bit-copies of pos) to LDS slots;
//    after the cross-wave reduce, threads locate the winning slot by ballot
//    match and read coords via LDS broadcast -- no global centroid load on
//    the serial chain.
// Exact-match discipline: contract off, ((dx^2+dy^2)+dz^2) order, skip
// margin 0.99999 (conservative vs <2e-6 fp error, unchanged from r14).
// ---------------------------------------------------------------------------
__global__ __launch_bounds__(1024, 4) void fps_kernel(const float* __restrict__ pos,
                                                      float* __restrict__ centers,
                                                      float* __restrict__ sbuf){
#pragma clang fp contract(off)
  __shared__ int hist[4096];
  __shared__ int ts[1024];
  __shared__ unsigned short perm[16384];
  __shared__ unsigned long long lslotK[2][16];
  __shared__ float lslotX[2][16], lslotY[2][16], lslotZ[2][16];
  const int b = blockIdx.x;
  const int t = threadIdx.x;
  const int wid = t >> 6, lane = t & 63;
  const float* pb = pos + (size_t)b * NPTS * 3;
  float* ssx = sbuf + (size_t)b * 3 * NPTS;
  float* ssy = ssx + NPTS;
  float* ssz = ssy + NPTS;
  const int p0 = t * 16;

  // ---- phase 0: load raw points, Morton cell ids ----
  float c[48];
  {
    const float4* src = (const float4*)(pb + (size_t)t*48);
#pragma unroll
    for (int q = 0; q < 12; ++q) *(float4*)&c[q*4] = src[q];
  }
  int cell[16];
#pragma unroll
  for (int j = 0; j < 16; ++j){
    float x = c[3*j], y = c[3*j+1], z = c[3*j+2];
    int ix = (int)(x * 16.f); ix = ix < 0 ? 0 : (ix > 15 ? 15 : ix);
    int iy = (int)(y * 16.f); iy = iy < 0 ? 0 : (iy > 15 ? 15 : iy);
    int iz = (int)(z * 16.f); iz = iz < 0 ? 0 : (iz > 15 ? 15 : iz);
    int m = 0;
#pragma unroll
    for (int k = 0; k < 4; ++k){
      m |= ((ix >> k) & 1) << (3*k + 2);
      m |= ((iy >> k) & 1) << (3*k + 1);
      m |= ((iz >> k) & 1) << (3*k + 0);
    }
    cell[j] = m;
  }
  // histogram
#pragma unroll
  for (int i = 0; i < 4; ++i) hist[t*4 + i] = 0;
  __syncthreads();
#pragma unroll
  for (int j = 0; j < 16; ++j) atomicAdd(&hist[cell[j]], 1);
  __syncthreads();
  // prefix sum: per-thread 4 cells -> Hillis-Steele over 1024 thread sums
  int h0 = hist[t*4], h1 = hist[t*4+1], h2v = hist[t*4+2];
  ts[t] = h0 + h1 + h2v + hist[t*4+3];
  __syncthreads();
  for (int off = 1; off < 1024; off <<= 1){
    int add = (t >= off) ? ts[t - off] : 0;
    __syncthreads();
    ts[t] += add;
    __syncthreads();
  }
  {
    int base = (t == 0) ? 0 : ts[t-1];
    hist[t*4]   = base;
    hist[t*4+1] = base + h0;
    hist[t*4+2] = base + h0 + h1;
    hist[t*4+3] = base + h0 + h1 + h2v;
  }
  __syncthreads();
  // scatter sorted coords to global scratch; permutation to LDS
#pragma unroll
  for (int j = 0; j < 16; ++j){
    int dst = atomicAdd(&hist[cell[j]], 1);
    ssx[dst] = c[3*j];
    ssy[dst] = c[3*j+1];
    ssz[dst] = c[3*j+2];
    perm[dst] = (unsigned short)(p0 + j);
  }
  __syncthreads();

  // ---- reload sorted points into registers; box; orig-idx pairs ----
  v2f px[8], py[8], pz[8], dist[8];
  int perm_reg[8];
#pragma unroll
  for (int g = 0; g < 4; ++g){
    float4 vx = *(const float4*)&ssx[p0 + g*4];
    float4 vy = *(const float4*)&ssy[p0 + g*4];
    float4 vz = *(const float4*)&ssz[p0 + g*4];
    px[g*2]   = (v2f){vx.x, vx.y}; px[g*2+1] = (v2f){vx.z, vx.w};
    py[g*2]   = (v2f){vy.x, vy.y}; py[g*2+1] = (v2f){vy.z, vy.w};
    pz[g*2]   = (v2f){vz.x, vz.y}; pz[g*2+1] = (v2f){vz.z, vz.w};
  }
#pragma unroll
  for (int j = 0; j < 8; ++j){
    perm_reg[j] = (int)perm[p0 + 2*j] | ((int)perm[p0 + 2*j + 1] << 16);
  }
  float bxl = 1e30f, bxh = -1e30f, byl = 1e30f, byh = -1e30f;
  float bzl = 1e30f, bzh = -1e30f;
#pragma unroll
  for (int j = 0; j < 8; ++j){
    asm volatile("" : "+v"(px[j]), "+v"(py[j]), "+v"(pz[j]), "+v"(perm_reg[j]));
    bxl = fminf(bxl, fminf(px[j].x, px[j].y));
    bxh = fmaxf(bxh, fmaxf(px[j].x, px[j].y));
    byl = fminf(byl, fminf(py[j].x, py[j].y));
    byh = fmaxf(byh, fmaxf(py[j].x, py[j].y));
    bzl = fminf(bzl, fminf(pz[j].x, pz[j].y));
    bzh = fmaxf(bzh, fmaxf(pz[j].x, pz[j].y));
    dist[j] = (v2f){1e10f, 1e10f};
  }
  float ub = 1e10f;
  int mi = 0;
  unsigned long long key = 0;
  int iswin = 0;
  float cx = pb[0], cy = pb[1], cz = pb[2];    // far=0 initial centroid

  // ---- phase 1: the serial FPS loop ----
  for (int s = 0; s < S; ++s){
    if (t == 0){
      float* cd = centers + (size_t)(b*S + s)*3;
      cd[0] = cx; cd[1] = cy; cd[2] = cz;
    }
    // box skip test (conservative margin: provably no dist changes)
    float lx = fmaxf(fmaxf(bxl - cx, cx - bxh), 0.f);
    float ly = fmaxf(fmaxf(byl - cy, cy - byh), 0.f);
    float lz = fmaxf(fmaxf(bzl - cz, cz - bzh), 0.f);
    float lb2 = ((lx*lx + ly*ly) + lz*lz);
    bool act = !(lb2 * 0.99999f >= ub);
    unsigned long long am = __ballot((int)act);
    if (am){                               // wave-uniform: someone is active
      if (act){
        v2f cx2 = (v2f){cx, cx}, cy2 = (v2f){cy, cy}, cz2 = (v2f){cz, cz};
        float nb = 0.0f;
#pragma unroll
        for (int j = 0; j < 8; ++j){
          v2f dx = px[j] - cx2;
          v2f dy = py[j] - cy2;
          v2f dz = pz[j] - cz2;
          v2f t1 = dx * dx;
          v2f t2 = dy * dy;
          v2f t3 = dz * dz;
          v2f d  = (t1 + t2) + t3;         // ((dx^2+dy^2)+dz^2)
          v2f od = dist[j];
          v2f nd = (v2f){__builtin_fminf(od.x, d.x), __builtin_fminf(od.y, d.y)};
          dist[j] = nd;
          nb = fmaxf(fmaxf(nb, nd.x), nd.y);   // v_max3
        }
        ub = nb;
        // locate: min orig index among this thread's dist==ub slots
        int m2 = 0x7fffffff;
#pragma unroll
        for (int j = 0; j < 8; ++j){
          if (dist[j].x == ub){ int o = perm_reg[j] & 0xffff;          m2 = o < m2 ? o : m2; }
          if (dist[j].y == ub){ int o = (perm_reg[j] >> 16) & 0xffff;  m2 = o < m2 ? o : m2; }
        }
        mi = m2;
        key = ((unsigned long long)__float_as_uint(ub) << 15)
            | (unsigned long long)(16384 - mi);
      }
      // single u64 wave max chain
      unsigned long long wk = key;
      DPP_MAXK0(DPP_ROW_SHR1,   wk);
      DPP_MAXK0(DPP_ROW_SHR2,   wk);
      DPP_MAXK0(DPP_ROW_SHR4,   wk);
      DPP_MAXK0(DPP_ROW_SHR8,   wk);
      DPP_MAXK0(DPP_ROW_BCAST15, wk);
      DPP_MAXK0(DPP_ROW_BCAST31, wk);      // lane 63 = wave max
      unsigned klo = (unsigned)__builtin_amdgcn_readlane((int)(unsigned)wk, 63);
      unsigned khi = (unsigned)__builtin_amdgcn_readlane((int)(unsigned)(wk >> 32), 63);
      unsigned long long kmax = (((unsigned long long)khi) << 32) | klo;
      unsigned long long wmask = __ballot((int)(key == kmax));
      iswin = (lane == (int)__builtin_ctzll(wmask));
    }
    const int par = s & 1;
    if (iswin){
      // derive coords of point mi from registers (exactly one slot matches)
      float wx = cx, wy = cy, wz = cz;
#pragma unroll
      for (int j = 0; j < 8; ++j){
        if ((perm_reg[j] & 0xffff) == mi)        { wx = px[j].x; wy = py[j].x; wz = pz[j].x; }
        if (((perm_reg[j] >> 16) & 0xffff) == mi){ wx = px[j].y; wy = py[j].y; wz = pz[j].y; }
      }
      lslotK[par][wid] = key;
      lslotX[par][wid] = wx;
      lslotY[par][wid] = wy;
      lslotZ[par][wid] = wz;
    }
    __syncthreads();
    // cross-wave u64 reduce: 16 slots on lanes 0-15 of each row
    unsigned long long kk = lslotK[par][lane & 15];
    unsigned long long kko = kk;
    DPP_MAXK0(DPP_ROW_SHR1, kk);
    DPP_MAXK0(DPP_ROW_SHR2, kk);
    DPP_MAXK0(DPP_ROW_SHR4, kk);
    DPP_MAXK0(DPP_ROW_SHR8, kk);
    unsigned blo = (unsigned)__builtin_amdgcn_readlane((int)(unsigned)kk, 15);
    unsigned bhi = (unsigned)__builtin_amdgcn_readlane((int)(unsigned)(kk >> 32), 15);
    unsigned long long bkmax = (((unsigned long long)bhi) << 32) | blo;
    unsigned m16 = (unsigned)__ballot((int)(kko == bkmax)) & 0xffffu;
    int sidx = (int)__builtin_ctz(m16);
    cx = lslotX[par][sidx];              // uniform LDS broadcast
    cy = lslotY[par][sidx];
    cz = lslotZ[par][sidx];
  }
}

// ---------------------------------------------------------------------------
// Ball query: one wave per center. Ordered compaction of the first 32
// in-radius indices (ascending index order == jnp.sort-then-truncate).
// ---------------------------------------------------------------------------
__global__ __launch_bounds__(256) void ballq_kernel(const float* __restrict__ pos,
                                                    const float* __restrict__ centers,
                                                    int* __restrict__ idx){
#pragma clang fp contract(off)
  const float R2 = (float)(0.2*0.2);   // match Python double 0.2*0.2 -> f32
  int wid  = blockIdx.x*4 + (threadIdx.x >> 6);
  int lane = threadIdx.x & 63;
  int b = wid >> 10;                   // wid / S
  const float* pb = pos + (size_t)b * NPTS * 3;
  float cx = centers[wid*3+0], cy = centers[wid*3+1], cz = centers[wid*3+2];
  int* out = idx + wid*KNEI;
  int count = 0; int first = -1;
  for (int base = 0; base < NPTS; base += 64){
    int p = base + lane;
    float dx = pb[p*3+0]-cx, dy = pb[p*3+1]-cy, dz = pb[p*3+2]-cz;
    float t1 = dx*dx, t2 = dy*dy, t3 = dz*dz;
    float d = (t1 + t2) + t3;
    bool inr = d <= R2;
    unsigned long long mask = __ballot(inr);
    if (count == 0 && mask) first = base + __builtin_ctzll(mask);
    if (inr){
      int slot = count + __popcll(mask & ((1ull << lane) - 1ull));
      if (slot < KNEI) out[slot] = p;
    }
    count += __popcll(mask);
    if (count >= KNEI) break;
  }
  if (count < KNEI){
    for (int slot = count + lane; slot < KNEI; slot += 64) out[slot] = first;
  }
}

// ---------------------------------------------------------------------------
// GEMM1 sem: h1[m][0:64] = feat[b, idx[m], :] @ w(64x64) + bias.
// Block: 256 threads, 64-row tile. Also accumulates per-channel sum/sumsq.
// ---------------------------------------------------------------------------
__global__ __launch_bounds__(256) void gemm_sem1(const float* __restrict__ feat,
    const int* __restrict__ idx, const float* __restrict__ w,
    const float* __restrict__ bias, float* __restrict__ h1,
    float* __restrict__ stat){
  __shared__ float xs[64][68];
  __shared__ float wsh[64][64];
  const int tid = threadIdx.x;
  const int m0 = blockIdx.x * 64;
#pragma unroll
  for (int i = 0; i < 4; ++i){
    int q = tid + i*256;                 // 1024 quads of w (64x64)
    int r = q >> 4, c4 = q & 15;
    *(float4*)&wsh[r][c4*4] = *(const float4*)&w[r*64 + c4*4];
  }
#pragma unroll
  for (int i = 0; i < 4; ++i){
    int q = tid + i*256;                 // 1024 quads of x tile (64x64)
    int r = q >> 4, c4 = q & 15;
    int m = m0 + r;
    int nb = idx[m];
    int b = m >> 15;                     // m / (S*KNEI)
    const float* fr = feat + ((size_t)b*NPTS + nb)*64;
    *(float4*)&xs[r][c4*4] = *(const float4*)&fr[c4*4];
  }
  __syncthreads();
  const int g  = tid & 7;                // channel group: 8 channels
  const int rt = tid >> 3;               // 32 row-threads, 2 rows each
  const int r0 = rt * 2;
  float acc[2][8];
#pragma unroll
  for (int c = 0; c < 8; ++c){ float bb = bias[g*8+c]; acc[0][c] = bb; acc[1][c] = bb; }
  for (int k = 0; k < 64; ++k){
    float x0 = xs[r0][k], x1 = xs[r0+1][k];
    float4 wa = *(float4*)&wsh[k][g*8];
    float4 wb = *(float4*)&wsh[k][g*8+4];
    float wv[8] = {wa.x,wa.y,wa.z,wa.w,wb.x,wb.y,wb.z,wb.w};
#pragma unroll
    for (int c = 0; c < 8; ++c){ acc[0][c] += x0*wv[c]; acc[1][c] += x1*wv[c]; }
  }
#pragma unroll
  for (int r = 0; r < 2; ++r){
    float* dst = h1 + (size_t)(m0 + r0 + r)*64 + g*8;
    *(float4*)dst     = make_float4(acc[r][0],acc[r][1],acc[r][2],acc[r][3]);
    *(float4*)(dst+4) = make_float4(acc[r][4],acc[r][5],acc[r][6],acc[r][7]);
  }
  float ls[8], lq[8];
#pragma unroll
  for (int c = 0; c < 8; ++c){
    ls[c] = acc[0][c] + acc[1][c];
    lq[c] = acc[0][c]*acc[0][c] + acc[1][c]*acc[1][c];
  }
  __syncthreads();
  float* red  = &xs[0][0];
  float* redq = &wsh[0][0];
#pragma unroll
  for (int c = 0; c < 8; ++c){
    red[(g*8+c)*32 + rt]  = ls[c];
    redq[(g*8+c)*32 + rt] = lq[c];
  }
  __syncthreads();
  if (tid < 128){
    int c = tid & 63;
    const float* src = (tid < 64) ? red : redq;
    float a2 = 0.f;
    for (int i = 0; i < 32; ++i) a2 += src[c*32+i];
    atomicAdd(&stat[(tid < 64 ? 0 : 64) + c], a2);
  }
}

// ---------------------------------------------------------------------------
// GEMM2 (sem & geo layer 2): x = relu(a*hin+d) (folded BN1), out 128 ch.
// ---------------------------------------------------------------------------
__global__ __launch_bounds__(256) void gemm2_kernel(const float* __restrict__ hin,
    const float* __restrict__ abn, const float* __restrict__ dbn,
    const float* __restrict__ w, const float* __restrict__ bias,
    float* __restrict__ hout, float* __restrict__ stat){
  __shared__ float xs[64][68];
  __shared__ float wsh[64][128];
  const int tid = threadIdx.x;
  const int m0 = blockIdx.x * 64;
#pragma unroll
  for (int i = 0; i < 8; ++i){
    int q = tid + i*256;                 // 2048 quads of w (64x128)
    int r = q >> 5, c4 = q & 31;
    *(float4*)&wsh[r][c4*4] = *(const float4*)&w[r*128 + c4*4];
  }
#pragma unroll
  for (int i = 0; i < 4; ++i){
    int q = tid + i*256;
    int r = q >> 4, c4 = q & 15;
    float4 v  = *(const float4*)&hin[(size_t)(m0+r)*64 + c4*4];
    float4 av = *(const float4*)&abn[c4*4];
    float4 dv = *(const float4*)&dbn[c4*4];
    v.x = fmaxf(v.x*av.x + dv.x, 0.f);
    v.y = fmaxf(v.y*av.y + dv.y, 0.f);
    v.z = fmaxf(v.z*av.z + dv.z, 0.f);
    v.w = fmaxf(v.w*av.w + dv.w, 0.f);
    *(float4*)&xs[r][c4*4] = v;
  }
  __syncthreads();
  const int g  = tid & 15;               // 16 groups x 8 ch = 128
  const int rt = tid >> 4;               // 16 row-threads x 4 rows = 64
  const int r0 = rt * 4;
  float acc[4][8];
#pragma unroll
  for (int c = 0; c < 8; ++c){
    float bb = bias[g*8+c];
    acc[0][c]=bb; acc[1][c]=bb; acc[2][c]=bb; acc[3][c]=bb;
  }
  for (int k = 0; k < 64; ++k){
    float x0 = xs[r0][k], x1 = xs[r0+1][k], x2 = xs[r0+2][k], x3 = xs[r0+3][k];
    float4 wa = *(float4*)&wsh[k][g*8];
    float4 wb = *(float4*)&wsh[k][g*8+4];
    float wv[8] = {wa.x,wa.y,wa.z,wa.w,wb.x,wb.y,wb.z,wb.w};
#pragma unroll
    for (int c = 0; c < 8; ++c){
      acc[0][c] += x0*wv[c]; acc[1][c] += x1*wv[c];
      acc[2][c] += x2*wv[c]; acc[3][c] += x3*wv[c];
    }
  }
#pragma unroll
  for (int r = 0; r < 4; ++r){
    float* dst = hout + (size_t)(m0 + r0 + r)*128 + g*8;
    *(float4*)dst     = make_float4(acc[r][0],acc[r][1],acc[r][2],acc[r][3]);
    *(float4*)(dst+4) = make_float4(acc[r][4],acc[r][5],acc[r][6],acc[r][7]);
  }
  float ls[8], lq[8];
#pragma unroll
  for (int c = 0; c < 8; ++c){
    ls[c] = acc[0][c]+acc[1][c]+acc[2][c]+acc[3][c];
    lq[c] = acc[0][c]*acc[0][c]+acc[1][c]*acc[1][c]+acc[2][c]*acc[2][c]+acc[3][c]*acc[3][c];
  }
  __syncthreads();
  float* red = &xs[0][0];                // 2048 sums + 2048 sumsq (fits 64*68)
#pragma unroll
  for (int c = 0; c < 8; ++c){
    red[(g*8+c)*16 + rt]        = ls[c];
    red[2048 + (g*8+c)*16 + rt] = lq[c];
  }
  __syncthreads();
  {
    int c = tid & 127;
    int isq = tid >> 7;
    float a2 = 0.f;
    for (int i = 0; i < 16; ++i) a2 += red[isq*2048 + c*16 + i];
    atomicAdd(&stat[isq*128 + c], a2);
  }
}

// ---------------------------------------------------------------------------
// GEMM1 geo: x = [center(3) | grouped_pos(3)] (6 ch) @ w(6x64) + bias.
// ---------------------------------------------------------------------------
__global__ __launch_bounds__(256) void gemm_geo1(const float* __restrict__ pos,
    const float* __restrict__ centers, const int* __restrict__ idx,
    const float* __restrict__ w, const float* __restrict__ bias,
    float* __restrict__ hout, float* __restrict__ stat){
  __shared__ float xs[64][8];
  __shared__ float wsh[6][64];
  __shared__ float red[2048];
  __shared__ float redq[2048];
  const int tid = threadIdx.x;
  const int m0 = blockIdx.x * 64;
  for (int i = tid; i < 384; i += 256) wsh[i >> 6][i & 63] = w[i];
  if (tid < 64){
    int m = m0 + tid;
    int grp = m >> 5;                    // m / KNEI
    int b = m >> 15;
    int nb = idx[m];
    const float* cp = centers + (size_t)grp*3;
    const float* pp = pos + ((size_t)b*NPTS + nb)*3;
    xs[tid][0]=cp[0]; xs[tid][1]=cp[1]; xs[tid][2]=cp[2];
    xs[tid][3]=pp[0]; xs[tid][4]=pp[1]; xs[tid][5]=pp[2];
  }
  __syncthreads();
  const int g  = tid & 7;
  const int rt = tid >> 3;
  const int r0 = rt * 2;
  float acc[2][8];
#pragma unroll
  for (int c = 0; c < 8; ++c){ float bb = bias[g*8+c]; acc[0][c]=bb; acc[1][c]=bb; }
#pragma unroll
  for (int k = 0; k < 6; ++k){
    float x0 = xs[r0][k], x1 = xs[r0+1][k];
    float4 wa = *(float4*)&wsh[k][g*8];
    float4 wb = *(float4*)&wsh[k][g*8+4];
    float wv[8] = {wa.x,wa.y,wa.z,wa.w,wb.x,wb.y,wb.z,wb.w};
#pragma unroll
    for (int c = 0; c < 8; ++c){ acc[0][c] += x0*wv[c]; acc[1][c] += x1*wv[c]; }
  }
#pragma unroll
  for (int r = 0; r < 2; ++r){
    float* dst = hout + (size_t)(m0 + r0 + r)*64 + g*8;
    *(float4*)dst     = make_float4(acc[r][0],acc[r][1],acc[r][2],acc[r][3]);
    *(float4*)(dst+4) = make_float4(acc[r][4],acc[r][5],acc[r][6],acc[r][7]);
  }
  float ls[8], lq[8];
#pragma unroll
  for (int c = 0; c < 8; ++c){
    ls[c] = acc[0][c] + acc[1][c];
    lq[c] = acc[0][c]*acc[0][c] + acc[1][c]*acc[1][c];
  }
#pragma unroll
  for (int c = 0; c < 8; ++c){
    red[(g*8+c)*32 + rt]  = ls[c];
    redq[(g*8+c)*32 + rt] = lq[c];
  }
  __syncthreads();
  if (tid < 128){
    int c = tid & 63;
    const float* src = (tid < 64) ? red : redq;
    float a2 = 0.f;
    for (int i = 0; i < 32; ++i) a2 += src[c*32+i];
    atomicAdd(&stat[(tid < 64 ? 0 : 64) + c], a2);
  }
}

// ---------------------------------------------------------------------------
// BN finalize: fold stats into per-channel scale/shift a,d.
// ---------------------------------------------------------------------------
__global__ void bn_finalize(const float* __restrict__ stat,
                            const float* __restrict__ gam, const float* __restrict__ bet,
                            float* __restrict__ a, float* __restrict__ d, int C){
  int c = threadIdx.x;
  if (c >= C) return;
  const float invM = 1.0f / (float)MROWS;
  float mu  = stat[c] * invM;
  float ex2 = stat[C + c] * invM;
  float var = ex2 - mu*mu;
  float aa = gam[c] * rsqrtf(var + 1e-5f);
  a[c] = aa;
  d[c] = bet[c] - mu*aa;
}

// ---------------------------------------------------------------------------
// Max over K with folded BN2 + ReLU: out[grp][c] = relu(max_k (a*h+d)).
// ---------------------------------------------------------------------------
__global__ __launch_bounds__(256) void maxpool_kernel(const float* __restrict__ hin,
    const float* __restrict__ abn, const float* __restrict__ dbn,
    float* __restrict__ out){
  const int tid = threadIdx.x;
  const int grp = blockIdx.x*8 + (tid >> 5);
  const int c4 = tid & 31;
  const float* base = hin + (size_t)grp*KNEI*128 + c4*4;
  float4 a = *(const float4*)&abn[c4*4];
  float4 d = *(const float4*)&dbn[c4*4];
  float4 m = make_float4(-3.4e38f,-3.4e38f,-3.4e38f,-3.4e38f);
  for (int k = 0; k < KNEI; ++k){
    float4 v = *(const float4*)&base[(size_t)k*128];
    m.x = fmaxf(m.x, v.x*a.x + d.x);
    m.y = fmaxf(m.y, v.y*a.y + d.y);
    m.z = fmaxf(m.z, v.z*a.z + d.z);
    m.w = fmaxf(m.w, v.w*a.w + d.w);
  }
  m.x = fmaxf(m.x, 0.f); m.y = fmaxf(m.y, 0.f);
  m.z = fmaxf(m.z, 0.f); m.w = fmaxf(m.w, 0.f);
  *(float4*)&out[(size_t)grp*128 + c4*4] = m;
}

__global__ void zero_kernel(float* __restrict__ p, int n){
  int i = blockIdx.x*blockDim.x + threadIdx.x;
  if (i < n) p[i] = 0.f;
}

extern "C" void kernel_launch(void* const* d_in, const int* in_sizes, int n_in,
                              void* d_out, int out_size, void* d_ws, size_t ws_size,
                              hipStream_t stream){
  const float* pos   = (const float*)d_in[0];
  const float* feat  = (const float*)d_in[1];
  const float* w_s1  = (const float*)d_in[2];
  const float* b_s1  = (const float*)d_in[3];
  const float* g_s1  = (const float*)d_in[4];
  const float* be_s1 = (const float*)d_in[5];
  const float* w_s2  = (const float*)d_in[6];
  const float* b_s2  = (const float*)d_in[7];
  const float* g_s2  = (const float*)d_in[8];
  const float* be_s2 = (const float*)d_in[9];
  const float* w_g1  = (const float*)d_in[10];
  const float* b_g1  = (const float*)d_in[11];
  const float* g_g1  = (const float*)d_in[12];
  const float* be_g1 = (const float*)d_in[13];
  const float* w_g2  = (const float*)d_in[14];
  const float* b_g2  = (const float*)d_in[15];
  const float* g_g2  = (const float*)d_in[16];
  const float* be_g2 = (const float*)d_in[17];
  float* outp = (float*)d_out;
  float* wsf  = (float*)d_ws;

  // workspace layout (floats):
  float* centers = wsf;                         // 8192*3 = 24576
  int*   idxp    = (int*)(wsf + 24576);         // 262144
  float* stats   = wsf + 24576 + 262144;        // 768
  float* bnad    = stats + 768;                 // 768
  float* h1      = wsf + 288256;                // 262144*64
  float* h2      = h1 + (size_t)MROWS*64;       // 262144*128
  // total = 50,619,904 floats = ~193.1 MiB
  // fps sorted-coords scratch lives at the head of h2 (8*3*16384 floats =
  // 1.5 MB) -- h2 is dead until gemm2, launched after fps completes.
  float* sortbuf = h2;

  float* st1 = stats;        // 64 sum + 64 sq
  float* st2 = stats + 128;  // 128 + 128
  float* st3 = stats + 384;  // 64 + 64
  float* st4 = stats + 512;  // 128 + 128
  float* a1 = bnad;        float* d1 = bnad + 64;
  float* a2 = bnad + 128;  float* d2 = bnad + 256;
  float* a3 = bnad + 384;  float* d3 = bnad + 448;
  float* a4 = bnad + 512;  float* d4 = bnad + 640;

  zero_kernel<<<3, 256, 0, stream>>>(stats, 768);
  fps_kernel<<<NB, 1024, 0, stream>>>(pos, centers, sortbuf);
  ballq_kernel<<<(NB*S)/4, 256, 0, stream>>>(pos, centers, idxp);

  // sem branch
  gemm_sem1<<<MROWS/64, 256, 0, stream>>>(feat, idxp, w_s1, b_s1, h1, st1);
  bn_finalize<<<1, 128, 0, stream>>>(st1, g_s1, be_s1, a1, d1, 64);
  gemm2_kernel<<<MROWS/64, 256, 0, stream>>>(h1, a1, d1, w_s2, b_s2, h2, st2);
  bn_finalize<<<1, 128, 0, stream>>>(st2, g_s2, be_s2, a2, d2, 128);
  maxpool_kernel<<<(NB*S)/8, 256, 0, stream>>>(h2, a2, d2, outp);

  // geo branch (reuses h1/h2)
  gemm_geo1<<<MROWS/64, 256, 0, stream>>>(pos, centers, idxp, w_g1, b_g1, h1, st3);
  bn_finalize<<<1, 128, 0, stream>>>(st3, g_g1, be_g1, a3, d3, 64);
  gemm2_kernel<<<MROWS/64, 256, 0, stream>>>(h1, a3, d3, w_g2, b_g2, h2, st4);
  bn_finalize<<<1, 128, 0, stream>>>(st4, g_g2, be_g2, a4, d4, 128);
  maxpool_kernel<<<(NB*S)/8, 256, 0, stream>>>(h2, a4, d4, outp + (size_t)NB*S*128);
}

// Round 8
// 2052.646 us; speedup vs baseline: 1.1352x; 1.1352x over previous
//
#include <hip/hip_runtime.h>

#define NB 8
#define NPTS 16384
#define S 1024
#define KNEI 32
#define MROWS (NB*S*KNEI)   // 262144

typedef float v2f __attribute__((ext_vector_type(2)));

// Value-only f32 max combine via DPP, bound_ctrl=1 (invalid lanes read 0 --
// safe identity: all reduced values are >= 0).
#define DPP_MAXF0(CTRL, v) do {                                               \
    int _o = __builtin_amdgcn_update_dpp(0, __float_as_int(v),                \
                                         (CTRL), 0xF, 0xF, true);             \
    (v) = fmaxf((v), __int_as_float(_o));                                     \
  } while (0)

// i32 min combine via DPP, identity INT_MAX via the 'old' operand
// (bound_ctrl=false keeps old where the source lane is invalid).
#define DPP_MINI(CTRL, v) do {                                                \
    int _o = __builtin_amdgcn_update_dpp((int)0x7fffffff, (v),                \
                                         (CTRL), 0xF, 0xF, false);            \
    (v) = (_o < (v)) ? _o : (v);                                              \
  } while (0)

// u64 key max combine via DPP halves, bound_ctrl=1 (identity 0 always loses:
// every real key >= 1 because of the 16384-idx field). Used ONLY in the
// 4-stage cross-wave reduce (16 slots) -- r15 showed it is too expensive
// for the 6-stage in-wave chain.
#define DPP_MAXK0(CTRL, k) do {                                               \
    int _olo = __builtin_amdgcn_update_dpp(0, (int)(unsigned)(k),             \
                                           (CTRL), 0xF, 0xF, true);           \
    int _ohi = __builtin_amdgcn_update_dpp(0, (int)(unsigned)((k) >> 32),     \
                                           (CTRL), 0xF, 0xF, true);           \
    unsigned long long _ok = (((unsigned long long)(unsigned)_ohi) << 32)     \
                           | (unsigned)_olo;                                  \
    if (_ok > (k)) (k) = _ok;                                                 \
  } while (0)

#define DPP_ROW_SHR1   0x111
#define DPP_ROW_SHR2   0x112
#define DPP_ROW_SHR4   0x114
#define DPP_ROW_SHR8   0x118
#define DPP_ROW_BCAST15 0x142
#define DPP_ROW_BCAST31 0x143

// ---------------------------------------------------------------------------
// FPS r16 = r14's proven chains (f32 max chain + guarded locate + i32 min
// chain; r15's single u64 in-wave chain cost +43% issue and is reverted)
// + two new pieces:
//  * WAVE-LEVEL RESULT CACHING: if ballot(act)==0 the wave's dist[] state is
//    untouched, so the cached (bmw, miw), winner lane, and winner coords are
//    still exact -- skip all three chains; the cached winner lane just
//    republishes key+coords to the current parity slot.
//  * coords published via LDS slots (winner lane derives them from its own
//    registers by matching miw) -- removes the scattered global centroid
//    load from the serial chain.
// Box-skip, Morton binning, perm_reg, key layout unchanged from r14/r15.
// Exact-match discipline: contract off, ((dx^2+dy^2)+dz^2) order, key =
// dist_bits<<15 | (16384-orig_idx) == numpy first-occurrence argmax.
// ---------------------------------------------------------------------------
__global__ __launch_bounds__(1024, 4) void fps_kernel(const float* __restrict__ pos,
                                                      float* __restrict__ centers,
                                                      float* __restrict__ sbuf){
#pragma clang fp contract(off)
  __shared__ int hist[4096];
  __shared__ int ts[1024];
  __shared__ unsigned short perm[16384];
  __shared__ unsigned long long lslotK[2][16];
  __shared__ float lslotX[2][16], lslotY[2][16], lslotZ[2][16];
  const int b = blockIdx.x;
  const int t = threadIdx.x;
  const int wid = t >> 6, lane = t & 63;
  const float* pb = pos + (size_t)b * NPTS * 3;
  float* ssx = sbuf + (size_t)b * 3 * NPTS;
  float* ssy = ssx + NPTS;
  float* ssz = ssy + NPTS;
  const int p0 = t * 16;

  // ---- phase 0: load raw points, Morton cell ids ----
  float c[48];
  {
    const float4* src = (const float4*)(pb + (size_t)t*48);
#pragma unroll
    for (int q = 0; q < 12; ++q) *(float4*)&c[q*4] = src[q];
  }
  int cell[16];
#pragma unroll
  for (int j = 0; j < 16; ++j){
    float x = c[3*j], y = c[3*j+1], z = c[3*j+2];
    int ix = (int)(x * 16.f); ix = ix < 0 ? 0 : (ix > 15 ? 15 : ix);
    int iy = (int)(y * 16.f); iy = iy < 0 ? 0 : (iy > 15 ? 15 : iy);
    int iz = (int)(z * 16.f); iz = iz < 0 ? 0 : (iz > 15 ? 15 : iz);
    int m = 0;
#pragma unroll
    for (int k = 0; k < 4; ++k){
      m |= ((ix >> k) & 1) << (3*k + 2);
      m |= ((iy >> k) & 1) << (3*k + 1);
      m |= ((iz >> k) & 1) << (3*k + 0);
    }
    cell[j] = m;
  }
  // histogram
#pragma unroll
  for (int i = 0; i < 4; ++i) hist[t*4 + i] = 0;
  __syncthreads();
#pragma unroll
  for (int j = 0; j < 16; ++j) atomicAdd(&hist[cell[j]], 1);
  __syncthreads();
  // prefix sum: per-thread 4 cells -> Hillis-Steele over 1024 thread sums
  int h0 = hist[t*4], h1 = hist[t*4+1], h2v = hist[t*4+2];
  ts[t] = h0 + h1 + h2v + hist[t*4+3];
  __syncthreads();
  for (int off = 1; off < 1024; off <<= 1){
    int add = (t >= off) ? ts[t - off] : 0;
    __syncthreads();
    ts[t] += add;
    __syncthreads();
  }
  {
    int base = (t == 0) ? 0 : ts[t-1];
    hist[t*4]   = base;
    hist[t*4+1] = base + h0;
    hist[t*4+2] = base + h0 + h1;
    hist[t*4+3] = base + h0 + h1 + h2v;
  }
  __syncthreads();
  // scatter sorted coords to global scratch; permutation to LDS
#pragma unroll
  for (int j = 0; j < 16; ++j){
    int dst = atomicAdd(&hist[cell[j]], 1);
    ssx[dst] = c[3*j];
    ssy[dst] = c[3*j+1];
    ssz[dst] = c[3*j+2];
    perm[dst] = (unsigned short)(p0 + j);
  }
  __syncthreads();

  // ---- reload sorted points into registers; box; orig-idx pairs ----
  v2f px[8], py[8], pz[8], dist[8];
  int perm_reg[8];
#pragma unroll
  for (int g = 0; g < 4; ++g){
    float4 vx = *(const float4*)&ssx[p0 + g*4];
    float4 vy = *(const float4*)&ssy[p0 + g*4];
    float4 vz = *(const float4*)&ssz[p0 + g*4];
    px[g*2]   = (v2f){vx.x, vx.y}; px[g*2+1] = (v2f){vx.z, vx.w};
    py[g*2]   = (v2f){vy.x, vy.y}; py[g*2+1] = (v2f){vy.z, vy.w};
    pz[g*2]   = (v2f){vz.x, vz.y}; pz[g*2+1] = (v2f){vz.z, vz.w};
  }
#pragma unroll
  for (int j = 0; j < 8; ++j){
    perm_reg[j] = (int)perm[p0 + 2*j] | ((int)perm[p0 + 2*j + 1] << 16);
  }
  float bxl = 1e30f, bxh = -1e30f, byl = 1e30f, byh = -1e30f;
  float bzl = 1e30f, bzh = -1e30f;
#pragma unroll
  for (int j = 0; j < 8; ++j){
    asm volatile("" : "+v"(px[j]), "+v"(py[j]), "+v"(pz[j]), "+v"(perm_reg[j]));
    bxl = fminf(bxl, fminf(px[j].x, px[j].y));
    bxh = fmaxf(bxh, fmaxf(px[j].x, px[j].y));
    byl = fminf(byl, fminf(py[j].x, py[j].y));
    byh = fmaxf(byh, fmaxf(py[j].x, py[j].y));
    bzl = fminf(bzl, fminf(pz[j].x, pz[j].y));
    bzh = fmaxf(bzh, fmaxf(pz[j].x, pz[j].y));
    dist[j] = (v2f){1e10f, 1e10f};
  }
  float ub = 1e10f;
  unsigned long long key = 0;
  int iswin = 0;
  float cwx = 0.f, cwy = 0.f, cwz = 0.f;       // winner lane's cached coords
  float cx = pb[0], cy = pb[1], cz = pb[2];    // far=0 initial centroid

  // ---- phase 1: the serial FPS loop ----
  for (int s = 0; s < S; ++s){
    if (t == 0){
      float* cd = centers + (size_t)(b*S + s)*3;
      cd[0] = cx; cd[1] = cy; cd[2] = cz;
    }
    // box skip test (conservative margin: provably no dist changes)
    float lx = fmaxf(fmaxf(bxl - cx, cx - bxh), 0.f);
    float ly = fmaxf(fmaxf(byl - cy, cy - byh), 0.f);
    float lz = fmaxf(fmaxf(bzl - cz, cz - bzh), 0.f);
    float lb2 = ((lx*lx + ly*ly) + lz*lz);
    bool act = !(lb2 * 0.99999f >= ub);
    unsigned long long am = __ballot((int)act);
    if (am){                               // wave-uniform branch
      if (act){
        v2f cx2 = (v2f){cx, cx}, cy2 = (v2f){cy, cy}, cz2 = (v2f){cz, cz};
        float nb = 0.0f;
#pragma unroll
        for (int j = 0; j < 8; ++j){
          v2f dx = px[j] - cx2;
          v2f dy = py[j] - cy2;
          v2f dz = pz[j] - cz2;
          v2f t1 = dx * dx;
          v2f t2 = dy * dy;
          v2f t3 = dz * dz;
          v2f d  = (t1 + t2) + t3;         // ((dx^2+dy^2)+dz^2)
          v2f od = dist[j];
          v2f nd = (v2f){__builtin_fminf(od.x, d.x), __builtin_fminf(od.y, d.y)};
          dist[j] = nd;
          nb = fmaxf(fmaxf(nb, nd.x), nd.y);   // v_max3
        }
        ub = nb;
      }
      // f32 wave value max (3 instrs/stage)
      float bv = ub;
      DPP_MAXF0(DPP_ROW_SHR1,   bv);
      DPP_MAXF0(DPP_ROW_SHR2,   bv);
      DPP_MAXF0(DPP_ROW_SHR4,   bv);
      DPP_MAXF0(DPP_ROW_SHR8,   bv);
      DPP_MAXF0(DPP_ROW_BCAST15, bv);
      DPP_MAXF0(DPP_ROW_BCAST31, bv);
      float bmw = __int_as_float(
          __builtin_amdgcn_readlane(__float_as_int(bv), 63));
      // guarded locate: min ORIGINAL index among dist==bmw (bit-exact match)
      int mi = 0x7fffffff;
      if (ub == bmw){
#pragma unroll
        for (int j = 0; j < 8; ++j){
          if (dist[j].x == bmw){ int o = perm_reg[j] & 0xffff;         mi = o < mi ? o : mi; }
          if (dist[j].y == bmw){ int o = (perm_reg[j] >> 16) & 0xffff; mi = o < mi ? o : mi; }
        }
      }
      DPP_MINI(DPP_ROW_SHR1,   mi);
      DPP_MINI(DPP_ROW_SHR2,   mi);
      DPP_MINI(DPP_ROW_SHR4,   mi);
      DPP_MINI(DPP_ROW_SHR8,   mi);
      DPP_MINI(DPP_ROW_BCAST15, mi);
      DPP_MINI(DPP_ROW_BCAST31, mi);
      int miw = __builtin_amdgcn_readlane(mi, 63);
      key = ((unsigned long long)__float_as_uint(bmw) << 15)
          | (unsigned long long)(16384 - miw);
      iswin = 0;
#pragma unroll
      for (int j = 0; j < 8; ++j){       // exactly one lane owns point miw
        if ((perm_reg[j] & 0xffff) == miw){
          cwx = px[j].x; cwy = py[j].x; cwz = pz[j].x; iswin = 1;
        }
        if (((perm_reg[j] >> 16) & 0xffff) == miw){
          cwx = px[j].y; cwy = py[j].y; cwz = pz[j].y; iswin = 1;
        }
      }
    }
    // publish (cached values when the wave skipped -- provably unchanged)
    const int par = s & 1;
    if (iswin){
      lslotK[par][wid] = key;
      lslotX[par][wid] = cwx;
      lslotY[par][wid] = cwy;
      lslotZ[par][wid] = cwz;
    }
    __syncthreads();
    // cross-wave u64 reduce: 16 slots on lanes 0-15 of each row
    unsigned long long kk = lslotK[par][lane & 15];
    unsigned long long kko = kk;
    DPP_MAXK0(DPP_ROW_SHR1, kk);
    DPP_MAXK0(DPP_ROW_SHR2, kk);
    DPP_MAXK0(DPP_ROW_SHR4, kk);
    DPP_MAXK0(DPP_ROW_SHR8, kk);
    unsigned blo = (unsigned)__builtin_amdgcn_readlane((int)(unsigned)kk, 15);
    unsigned bhi = (unsigned)__builtin_amdgcn_readlane((int)(unsigned)(kk >> 32), 15);
    unsigned long long bkmax = (((unsigned long long)bhi) << 32) | blo;
    unsigned m16 = (unsigned)__ballot((int)(kko == bkmax)) & 0xffffu;
    int sidx = (int)__builtin_ctz(m16);
    cx = lslotX[par][sidx];              // uniform LDS broadcast
    cy = lslotY[par][sidx];
    cz = lslotZ[par][sidx];
  }
}

// ---------------------------------------------------------------------------
// Ball query: one wave per center. Ordered compaction of the first 32
// in-radius indices (ascending index order == jnp.sort-then-truncate).
// ---------------------------------------------------------------------------
__global__ __launch_bounds__(256) void ballq_kernel(const float* __restrict__ pos,
                                                    const float* __restrict__ centers,
                                                    int* __restrict__ idx){
#pragma clang fp contract(off)
  const float R2 = (float)(0.2*0.2);   // match Python double 0.2*0.2 -> f32
  int wid  = blockIdx.x*4 + (threadIdx.x >> 6);
  int lane = threadIdx.x & 63;
  int b = wid >> 10;                   // wid / S
  const float* pb = pos + (size_t)b * NPTS * 3;
  float cx = centers[wid*3+0], cy = centers[wid*3+1], cz = centers[wid*3+2];
  int* out = idx + wid*KNEI;
  int count = 0; int first = -1;
  for (int base = 0; base < NPTS; base += 64){
    int p = base + lane;
    float dx = pb[p*3+0]-cx, dy = pb[p*3+1]-cy, dz = pb[p*3+2]-cz;
    float t1 = dx*dx, t2 = dy*dy, t3 = dz*dz;
    float d = (t1 + t2) + t3;
    bool inr = d <= R2;
    unsigned long long mask = __ballot(inr);
    if (count == 0 && mask) first = base + __builtin_ctzll(mask);
    if (inr){
      int slot = count + __popcll(mask & ((1ull << lane) - 1ull));
      if (slot < KNEI) out[slot] = p;
    }
    count += __popcll(mask);
    if (count >= KNEI) break;
  }
  if (count < KNEI){
    for (int slot = count + lane; slot < KNEI; slot += 64) out[slot] = first;
  }
}

// ---------------------------------------------------------------------------
// GEMM1 sem: h1[m][0:64] = feat[b, idx[m], :] @ w(64x64) + bias.
// Block: 256 threads, 64-row tile. Also accumulates per-channel sum/sumsq.
// ---------------------------------------------------------------------------
__global__ __launch_bounds__(256) void gemm_sem1(const float* __restrict__ feat,
    const int* __restrict__ idx, const float* __restrict__ w,
    const float* __restrict__ bias, float* __restrict__ h1,
    float* __restrict__ stat){
  __shared__ float xs[64][68];
  __shared__ float wsh[64][64];
  const int tid = threadIdx.x;
  const int m0 = blockIdx.x * 64;
#pragma unroll
  for (int i = 0; i < 4; ++i){
    int q = tid + i*256;                 // 1024 quads of w (64x64)
    int r = q >> 4, c4 = q & 15;
    *(float4*)&wsh[r][c4*4] = *(const float4*)&w[r*64 + c4*4];
  }
#pragma unroll
  for (int i = 0; i < 4; ++i){
    int q = tid + i*256;                 // 1024 quads of x tile (64x64)
    int r = q >> 4, c4 = q & 15;
    int m = m0 + r;
    int nb = idx[m];
    int b = m >> 15;                     // m / (S*KNEI)
    const float* fr = feat + ((size_t)b*NPTS + nb)*64;
    *(float4*)&xs[r][c4*4] = *(const float4*)&fr[c4*4];
  }
  __syncthreads();
  const int g  = tid & 7;                // channel group: 8 channels
  const int rt = tid >> 3;               // 32 row-threads, 2 rows each
  const int r0 = rt * 2;
  float acc[2][8];
#pragma unroll
  for (int c = 0; c < 8; ++c){ float bb = bias[g*8+c]; acc[0][c] = bb; acc[1][c] = bb; }
  for (int k = 0; k < 64; ++k){
    float x0 = xs[r0][k], x1 = xs[r0+1][k];
    float4 wa = *(float4*)&wsh[k][g*8];
    float4 wb = *(float4*)&wsh[k][g*8+4];
    float wv[8] = {wa.x,wa.y,wa.z,wa.w,wb.x,wb.y,wb.z,wb.w};
#pragma unroll
    for (int c = 0; c < 8; ++c){ acc[0][c] += x0*wv[c]; acc[1][c] += x1*wv[c]; }
  }
#pragma unroll
  for (int r = 0; r < 2; ++r){
    float* dst = h1 + (size_t)(m0 + r0 + r)*64 + g*8;
    *(float4*)dst     = make_float4(acc[r][0],acc[r][1],acc[r][2],acc[r][3]);
    *(float4*)(dst+4) = make_float4(acc[r][4],acc[r][5],acc[r][6],acc[r][7]);
  }
  float ls[8], lq[8];
#pragma unroll
  for (int c = 0; c < 8; ++c){
    ls[c] = acc[0][c] + acc[1][c];
    lq[c] = acc[0][c]*acc[0][c] + acc[1][c]*acc[1][c];
  }
  __syncthreads();
  float* red  = &xs[0][0];
  float* redq = &wsh[0][0];
#pragma unroll
  for (int c = 0; c < 8; ++c){
    red[(g*8+c)*32 + rt]  = ls[c];
    redq[(g*8+c)*32 + rt] = lq[c];
  }
  __syncthreads();
  if (tid < 128){
    int c = tid & 63;
    const float* src = (tid < 64) ? red : redq;
    float a2 = 0.f;
    for (int i = 0; i < 32; ++i) a2 += src[c*32+i];
    atomicAdd(&stat[(tid < 64 ? 0 : 64) + c], a2);
  }
}

// ---------------------------------------------------------------------------
// GEMM2 fused (sem & geo layer 2): x = relu(a*hin+d) (folded BN1), 128 out
// channels. Does NOT materialize h2: since BN2's scale a = gamma*rsqrt(var)
// with gamma==1 > 0 is positive, max_k(a*h+d) == a*(max_k h)+d exactly
// (monotone affine), so we reduce max over k per group IN-BLOCK and emit
// only 2x128 floats/block. Stats (sum/sumsq over all rows) unchanged.
// ---------------------------------------------------------------------------
__global__ __launch_bounds__(256) void gemm2_fused(const float* __restrict__ hin,
    const float* __restrict__ abn, const float* __restrict__ dbn,
    const float* __restrict__ w, const float* __restrict__ bias,
    float* __restrict__ hmax, float* __restrict__ stat){
  __shared__ float xs[64][68];
  __shared__ float wsh[64][128];
  const int tid = threadIdx.x;
  const int m0 = blockIdx.x * 64;
#pragma unroll
  for (int i = 0; i < 8; ++i){
    int q = tid + i*256;                 // 2048 quads of w (64x128)
    int r = q >> 5, c4 = q & 31;
    *(float4*)&wsh[r][c4*4] = *(const float4*)&w[r*128 + c4*4];
  }
#pragma unroll
  for (int i = 0; i < 4; ++i){
    int q = tid + i*256;
    int r = q >> 4, c4 = q & 15;
    float4 v  = *(const float4*)&hin[(size_t)(m0+r)*64 + c4*4];
    float4 av = *(const float4*)&abn[c4*4];
    float4 dv = *(const float4*)&dbn[c4*4];
    v.x = fmaxf(v.x*av.x + dv.x, 0.f);
    v.y = fmaxf(v.y*av.y + dv.y, 0.f);
    v.z = fmaxf(v.z*av.z + dv.z, 0.f);
    v.w = fmaxf(v.w*av.w + dv.w, 0.f);
    *(float4*)&xs[r][c4*4] = v;
  }
  __syncthreads();
  const int g  = tid & 15;               // 16 groups x 8 ch = 128
  const int rt = tid >> 4;               // 16 row-threads x 4 rows = 64
  const int r0 = rt * 4;                 // rows r0..r0+3 all in group rt>>3
  float acc[4][8];
#pragma unroll
  for (int c = 0; c < 8; ++c){
    float bb = bias[g*8+c];
    acc[0][c]=bb; acc[1][c]=bb; acc[2][c]=bb; acc[3][c]=bb;
  }
  for (int k = 0; k < 64; ++k){
    float x0 = xs[r0][k], x1 = xs[r0+1][k], x2 = xs[r0+2][k], x3 = xs[r0+3][k];
    float4 wa = *(float4*)&wsh[k][g*8];
    float4 wb = *(float4*)&wsh[k][g*8+4];
    float wv[8] = {wa.x,wa.y,wa.z,wa.w,wb.x,wb.y,wb.z,wb.w};
#pragma unroll
    for (int c = 0; c < 8; ++c){
      acc[0][c] += x0*wv[c]; acc[1][c] += x1*wv[c];
      acc[2][c] += x2*wv[c]; acc[3][c] += x3*wv[c];
    }
  }
  float ls[8], lq[8], tmax[8];
#pragma unroll
  for (int c = 0; c < 8; ++c){
    ls[c] = acc[0][c]+acc[1][c]+acc[2][c]+acc[3][c];
    lq[c] = acc[0][c]*acc[0][c]+acc[1][c]*acc[1][c]+acc[2][c]*acc[2][c]+acc[3][c]*acc[3][c];
    tmax[c] = fmaxf(fmaxf(acc[0][c],acc[1][c]), fmaxf(acc[2][c],acc[3][c]));
  }
  __syncthreads();
  float* red  = &xs[0][0];               // 2048 sums + 2048 sumsq (<= 64*68)
  float* mred = &wsh[0][0];              // 16 x 128 per-thread maxes
#pragma unroll
  for (int c = 0; c < 8; ++c){
    red[(g*8+c)*16 + rt]        = ls[c];
    red[2048 + (g*8+c)*16 + rt] = lq[c];
    mred[rt*128 + g*8 + c]      = tmax[c];
  }
  __syncthreads();
  {
    int c = tid & 127;
    int isq = tid >> 7;
    float a2 = 0.f;
    for (int i = 0; i < 16; ++i) a2 += red[isq*2048 + c*16 + i];
    atomicAdd(&stat[isq*128 + c], a2);
  }
  {
    int og = tid >> 7;                   // 0..1 (k-group within block)
    int c  = tid & 127;
    float m = -3.4e38f;
#pragma unroll
    for (int i = 0; i < 8; ++i) m = fmaxf(m, mred[(og*8 + i)*128 + c]);
    hmax[(size_t)(blockIdx.x*2 + og)*128 + c] = m;
  }
}

// ---------------------------------------------------------------------------
// GEMM1 geo: x = [center(3) | grouped_pos(3)] (6 ch) @ w(6x64) + bias.
// ---------------------------------------------------------------------------
__global__ __launch_bounds__(256) void gemm_geo1(const float* __restrict__ pos,
    const float* __restrict__ centers, const int* __restrict__ idx,
    const float* __restrict__ w, const float* __restrict__ bias,
    float* __restrict__ hout, float* __restrict__ stat){
  __shared__ float xs[64][8];
  __shared__ float wsh[6][64];
  __shared__ float red[2048];
  __shared__ float redq[2048];
  const int tid = threadIdx.x;
  const int m0 = blockIdx.x * 64;
  for (int i = tid; i < 384; i += 256) wsh[i >> 6][i & 63] = w[i];
  if (tid < 64){
    int m = m0 + tid;
    int grp = m >> 5;                    // m / KNEI
    int b = m >> 15;
    int nb = idx[m];
    const float* cp = centers + (size_t)grp*3;
    const float* pp = pos + ((size_t)b*NPTS + nb)*3;
    xs[tid][0]=cp[0]; xs[tid][1]=cp[1]; xs[tid][2]=cp[2];
    xs[tid][3]=pp[0]; xs[tid][4]=pp[1]; xs[tid][5]=pp[2];
  }
  __syncthreads();
  const int g  = tid & 7;
  const int rt = tid >> 3;
  const int r0 = rt * 2;
  float acc[2][8];
#pragma unroll
  for (int c = 0; c < 8; ++c){ float bb = bias[g*8+c]; acc[0][c]=bb; acc[1][c]=bb; }
#pragma unroll
  for (int k = 0; k < 6; ++k){
    float x0 = xs[r0][k], x1 = xs[r0+1][k];
    float4 wa = *(float4*)&wsh[k][g*8];
    float4 wb = *(float4*)&wsh[k][g*8+4];
    float wv[8] = {wa.x,wa.y,wa.z,wa.w,wb.x,wb.y,wb.z,wb.w};
#pragma unroll
    for (int c = 0; c < 8; ++c){ acc[0][c] += x0*wv[c]; acc[1][c] += x1*wv[c]; }
  }
#pragma unroll
  for (int r = 0; r < 2; ++r){
    float* dst = hout + (size_t)(m0 + r0 + r)*64 + g*8;
    *(float4*)dst     = make_float4(acc[r][0],acc[r][1],acc[r][2],acc[r][3]);
    *(float4*)(dst+4) = make_float4(acc[r][4],acc[r][5],acc[r][6],acc[r][7]);
  }
  float ls[8], lq[8];
#pragma unroll
  for (int c = 0; c < 8; ++c){
    ls[c] = acc[0][c] + acc[1][c];
    lq[c] = acc[0][c]*acc[0][c] + acc[1][c]*acc[1][c];
  }
#pragma unroll
  for (int c = 0; c < 8; ++c){
    red[(g*8+c)*32 + rt]  = ls[c];
    redq[(g*8+c)*32 + rt] = lq[c];
  }
  __syncthreads();
  if (tid < 128){
    int c = tid & 63;
    const float* src = (tid < 64) ? red : redq;
    float a2 = 0.f;
    for (int i = 0; i < 32; ++i) a2 += src[c*32+i];
    atomicAdd(&stat[(tid < 64 ? 0 : 64) + c], a2);
  }
}

// ---------------------------------------------------------------------------
// BN finalize: fold stats into per-channel scale/shift a,d.
// ---------------------------------------------------------------------------
__global__ void bn_finalize(const float* __restrict__ stat,
                            const float* __restrict__ gam, const float* __restrict__ bet,
                            float* __restrict__ a, float* __restrict__ d, int C){
  int c = threadIdx.x;
  if (c >= C) return;
  const float invM = 1.0f / (float)MROWS;
  float mu  = stat[c] * invM;
  float ex2 = stat[C + c] * invM;
  float var = ex2 - mu*mu;
  float aa = gam[c] * rsqrtf(var + 1e-5f);
  a[c] = aa;
  d[c] = bet[c] - mu*aa;
}

// ---------------------------------------------------------------------------
// BN apply on pooled maxes: out[i] = relu(a[c]*hmax[i]+d[c]).
// Exact vs old (maxpool over a*h+d): a>0 makes the affine monotone, so the
// max commutes with it bit-exactly.
// ---------------------------------------------------------------------------
__global__ __launch_bounds__(256) void bnapply_kernel(const float* __restrict__ hmax,
    const float* __restrict__ abn, const float* __restrict__ dbn,
    float* __restrict__ out){
  int i = blockIdx.x*256 + threadIdx.x;
  int c = i & 127;
  out[i] = fmaxf(hmax[i]*abn[c] + dbn[c], 0.f);
}

__global__ void zero_kernel(float* __restrict__ p, int n){
  int i = blockIdx.x*blockDim.x + threadIdx.x;
  if (i < n) p[i] = 0.f;
}

extern "C" void kernel_launch(void* const* d_in, const int* in_sizes, int n_in,
                              void* d_out, int out_size, void* d_ws, size_t ws_size,
                              hipStream_t stream){
  const float* pos   = (const float*)d_in[0];
  const float* feat  = (const float*)d_in[1];
  const float* w_s1  = (const float*)d_in[2];
  const float* b_s1  = (const float*)d_in[3];
  const float* g_s1  = (const float*)d_in[4];
  const float* be_s1 = (const float*)d_in[5];
  const float* w_s2  = (const float*)d_in[6];
  const float* b_s2  = (const float*)d_in[7];
  const float* g_s2  = (const float*)d_in[8];
  const float* be_s2 = (const float*)d_in[9];
  const float* w_g1  = (const float*)d_in[10];
  const float* b_g1  = (const float*)d_in[11];
  const float* g_g1  = (const float*)d_in[12];
  const float* be_g1 = (const float*)d_in[13];
  const float* w_g2  = (const float*)d_in[14];
  const float* b_g2  = (const float*)d_in[15];
  const float* g_g2  = (const float*)d_in[16];
  const float* be_g2 = (const float*)d_in[17];
  float* outp = (float*)d_out;
  float* wsf  = (float*)d_ws;

  // workspace layout (floats):
  float* centers = wsf;                         // 8192*3 = 24576
  int*   idxp    = (int*)(wsf + 24576);         // 262144
  float* stats   = wsf + 24576 + 262144;        // 768
  float* bnad    = stats + 768;                 // 768
  float* h1      = wsf + 288256;                // 262144*64
  float* scratch = h1 + (size_t)MROWS*64;       // former h2 region (free)
  // scratch usage: fps sorted coords (393216 f), then hmax1/hmax2 (1M f each)
  float* sortbuf = scratch;
  float* hmax1   = scratch + 524288;
  float* hmax2   = scratch + 524288 + 1048576;

  float* st1 = stats;        // 64 sum + 64 sq
  float* st2 = stats + 128;  // 128 + 128
  float* st3 = stats + 384;  // 64 + 64
  float* st4 = stats + 512;  // 128 + 128
  float* a1 = bnad;        float* d1 = bnad + 64;
  float* a2 = bnad + 128;  float* d2 = bnad + 256;
  float* a3 = bnad + 384;  float* d3 = bnad + 448;
  float* a4 = bnad + 512;  float* d4 = bnad + 640;

  zero_kernel<<<3, 256, 0, stream>>>(stats, 768);
  fps_kernel<<<NB, 1024, 0, stream>>>(pos, centers, sortbuf);
  ballq_kernel<<<(NB*S)/4, 256, 0, stream>>>(pos, centers, idxp);

  // sem branch
  gemm_sem1<<<MROWS/64, 256, 0, stream>>>(feat, idxp, w_s1, b_s1, h1, st1);
  bn_finalize<<<1, 128, 0, stream>>>(st1, g_s1, be_s1, a1, d1, 64);
  gemm2_fused<<<MROWS/64, 256, 0, stream>>>(h1, a1, d1, w_s2, b_s2, hmax1, st2);
  bn_finalize<<<1, 128, 0, stream>>>(st2, g_s2, be_s2, a2, d2, 128);
  bnapply_kernel<<<(NB*S*128)/256, 256, 0, stream>>>(hmax1, a2, d2, outp);

  // geo branch (reuses h1)
  gemm_geo1<<<MROWS/64, 256, 0, stream>>>(pos, centers, idxp, w_g1, b_g1, h1, st3);
  bn_finalize<<<1, 128, 0, stream>>>(st3, g_g1, be_g1, a3, d3, 64);
  gemm2_fused<<<MROWS/64, 256, 0, stream>>>(h1, a3, d3, w_g2, b_g2, hmax2, st4);
  bn_finalize<<<1, 128, 0, stream>>>(st4, g_g2, be_g2, a4, d4, 128);
  bnapply_kernel<<<(NB*S*128)/256, 256, 0, stream>>>(hmax2, a4, d4, outp + (size_t)NB*S*128);
}

// Round 9
// 1711.761 us; speedup vs baseline: 1.3612x; 1.1991x over previous
//
#include <hip/hip_runtime.h>

#define NB 8
#define NPTS 16384
#define S 1024
#define KNEI 32
#define MROWS (NB*S*KNEI)   // 262144

typedef float v2f __attribute__((ext_vector_type(2)));

// Value-only f32 max combine via DPP, bound_ctrl=1 (invalid lanes read 0 --
// safe identity: all reduced values are >= 0).
#define DPP_MAXF0(CTRL, v) do {                                               \
    int _o = __builtin_amdgcn_update_dpp(0, __float_as_int(v),                \
                                         (CTRL), 0xF, 0xF, true);             \
    (v) = fmaxf((v), __int_as_float(_o));                                     \
  } while (0)

// i32 min combine via DPP, identity INT_MAX via the 'old' operand
// (bound_ctrl=false keeps old where the source lane is invalid).
#define DPP_MINI(CTRL, v) do {                                                \
    int _o = __builtin_amdgcn_update_dpp((int)0x7fffffff, (v),                \
                                         (CTRL), 0xF, 0xF, false);            \
    (v) = (_o < (v)) ? _o : (v);                                              \
  } while (0)

// u64 key max combine via DPP halves, bound_ctrl=1 (identity 0 always loses:
// every real key >= 1 because of the 16384-idx field). Used ONLY in the
// 4-stage cross-wave reduce (r15 showed it's too costly for in-wave use).
#define DPP_MAXK0(CTRL, k) do {                                               \
    int _olo = __builtin_amdgcn_update_dpp(0, (int)(unsigned)(k),             \
                                           (CTRL), 0xF, 0xF, true);           \
    int _ohi = __builtin_amdgcn_update_dpp(0, (int)(unsigned)((k) >> 32),     \
                                           (CTRL), 0xF, 0xF, true);           \
    unsigned long long _ok = (((unsigned long long)(unsigned)_ohi) << 32)     \
                           | (unsigned)_olo;                                  \
    if (_ok > (k)) (k) = _ok;                                                 \
  } while (0)

#define DPP_ROW_SHR1   0x111
#define DPP_ROW_SHR2   0x112
#define DPP_ROW_SHR4   0x114
#define DPP_ROW_SHR8   0x118
#define DPP_ROW_BCAST15 0x142
#define DPP_ROW_BCAST31 0x143

// ---------------------------------------------------------------------------
// FPS r17 = r14's measured-best structure (1325us: f32 chain + guarded
// locate + i32 chain, lane-0 key publish, coords via uniform global load)
// + KEY-ONLY wave caching from r16 (the part that saved issue) WITHOUT
// r16's winner-coords scan (the part that added ~512 SIMD-cycles of
// pre-barrier latency and regressed to 1465us):
//   if ballot(act)==0: this wave's dist[] is untouched -> its cached
//   wave-reduced key is still exact; lane 0 republishes it and the wave
//   skips all three DPP chains (~76 instrs). Active path is byte-identical
//   to r14's.
// Morton binning, box-skip, perm_reg register-resident locate unchanged.
// Exact-match discipline: contract off, ((dx^2+dy^2)+dz^2) order, key =
// dist_bits<<15 | (16384-orig_idx) == numpy first-occurrence argmax.
// ---------------------------------------------------------------------------
__global__ __launch_bounds__(1024, 4) void fps_kernel(const float* __restrict__ pos,
                                                      float* __restrict__ centers,
                                                      float* __restrict__ sbuf){
#pragma clang fp contract(off)
  __shared__ int hist[4096];
  __shared__ int ts[1024];
  __shared__ unsigned short perm[16384];
  __shared__ unsigned long long lslotK[2][16];
  const int b = blockIdx.x;
  const int t = threadIdx.x;
  const int wid = t >> 6, lane = t & 63;
  const float* pb = pos + (size_t)b * NPTS * 3;
  float* ssx = sbuf + (size_t)b * 3 * NPTS;
  float* ssy = ssx + NPTS;
  float* ssz = ssy + NPTS;
  const int p0 = t * 16;

  // ---- phase 0: load raw points, Morton cell ids ----
  float c[48];
  {
    const float4* src = (const float4*)(pb + (size_t)t*48);
#pragma unroll
    for (int q = 0; q < 12; ++q) *(float4*)&c[q*4] = src[q];
  }
  int cell[16];
#pragma unroll
  for (int j = 0; j < 16; ++j){
    float x = c[3*j], y = c[3*j+1], z = c[3*j+2];
    int ix = (int)(x * 16.f); ix = ix < 0 ? 0 : (ix > 15 ? 15 : ix);
    int iy = (int)(y * 16.f); iy = iy < 0 ? 0 : (iy > 15 ? 15 : iy);
    int iz = (int)(z * 16.f); iz = iz < 0 ? 0 : (iz > 15 ? 15 : iz);
    int m = 0;
#pragma unroll
    for (int k = 0; k < 4; ++k){
      m |= ((ix >> k) & 1) << (3*k + 2);
      m |= ((iy >> k) & 1) << (3*k + 1);
      m |= ((iz >> k) & 1) << (3*k + 0);
    }
    cell[j] = m;
  }
  // histogram
#pragma unroll
  for (int i = 0; i < 4; ++i) hist[t*4 + i] = 0;
  __syncthreads();
#pragma unroll
  for (int j = 0; j < 16; ++j) atomicAdd(&hist[cell[j]], 1);
  __syncthreads();
  // prefix sum: per-thread 4 cells -> Hillis-Steele over 1024 thread sums
  int h0 = hist[t*4], h1 = hist[t*4+1], h2v = hist[t*4+2];
  ts[t] = h0 + h1 + h2v + hist[t*4+3];
  __syncthreads();
  for (int off = 1; off < 1024; off <<= 1){
    int add = (t >= off) ? ts[t - off] : 0;
    __syncthreads();
    ts[t] += add;
    __syncthreads();
  }
  {
    int base = (t == 0) ? 0 : ts[t-1];
    hist[t*4]   = base;
    hist[t*4+1] = base + h0;
    hist[t*4+2] = base + h0 + h1;
    hist[t*4+3] = base + h0 + h1 + h2v;
  }
  __syncthreads();
  // scatter sorted coords to global scratch; permutation to LDS
#pragma unroll
  for (int j = 0; j < 16; ++j){
    int dst = atomicAdd(&hist[cell[j]], 1);
    ssx[dst] = c[3*j];
    ssy[dst] = c[3*j+1];
    ssz[dst] = c[3*j+2];
    perm[dst] = (unsigned short)(p0 + j);
  }
  __syncthreads();

  // ---- reload sorted points into registers; box; orig-idx pairs ----
  v2f px[8], py[8], pz[8], dist[8];
  int perm_reg[8];
#pragma unroll
  for (int g = 0; g < 4; ++g){
    float4 vx = *(const float4*)&ssx[p0 + g*4];
    float4 vy = *(const float4*)&ssy[p0 + g*4];
    float4 vz = *(const float4*)&ssz[p0 + g*4];
    px[g*2]   = (v2f){vx.x, vx.y}; px[g*2+1] = (v2f){vx.z, vx.w};
    py[g*2]   = (v2f){vy.x, vy.y}; py[g*2+1] = (v2f){vy.z, vy.w};
    pz[g*2]   = (v2f){vz.x, vz.y}; pz[g*2+1] = (v2f){vz.z, vz.w};
  }
#pragma unroll
  for (int j = 0; j < 8; ++j){
    perm_reg[j] = (int)perm[p0 + 2*j] | ((int)perm[p0 + 2*j + 1] << 16);
  }
  float bxl = 1e30f, bxh = -1e30f, byl = 1e30f, byh = -1e30f;
  float bzl = 1e30f, bzh = -1e30f;
#pragma unroll
  for (int j = 0; j < 8; ++j){
    asm volatile("" : "+v"(px[j]), "+v"(py[j]), "+v"(pz[j]), "+v"(perm_reg[j]));
    bxl = fminf(bxl, fminf(px[j].x, px[j].y));
    bxh = fmaxf(bxh, fmaxf(px[j].x, px[j].y));
    byl = fminf(byl, fminf(py[j].x, py[j].y));
    byh = fmaxf(byh, fmaxf(py[j].x, py[j].y));
    bzl = fminf(bzl, fminf(pz[j].x, pz[j].y));
    bzh = fmaxf(bzh, fmaxf(pz[j].x, pz[j].y));
    dist[j] = (v2f){1e10f, 1e10f};
  }
  float ub = 1e10f;
  unsigned long long key = 0;                  // cached wave-reduced key
  float cx = pb[0], cy = pb[1], cz = pb[2];    // far=0 initial centroid

  // ---- phase 1: the serial FPS loop ----
  for (int s = 0; s < S; ++s){
    if (t == 0){
      float* cd = centers + (size_t)(b*S + s)*3;
      cd[0] = cx; cd[1] = cy; cd[2] = cz;
    }
    // box skip test (conservative margin: provably no dist changes)
    float lx = fmaxf(fmaxf(bxl - cx, cx - bxh), 0.f);
    float ly = fmaxf(fmaxf(byl - cy, cy - byh), 0.f);
    float lz = fmaxf(fmaxf(bzl - cz, cz - bzh), 0.f);
    float lb2 = ((lx*lx + ly*ly) + lz*lz);
    bool act = !(lb2 * 0.99999f >= ub);
    unsigned long long am = __ballot((int)act);
    if (am){                               // wave-uniform branch
      if (act){
        v2f cx2 = (v2f){cx, cx}, cy2 = (v2f){cy, cy}, cz2 = (v2f){cz, cz};
        float nb = 0.0f;
#pragma unroll
        for (int j = 0; j < 8; ++j){
          v2f dx = px[j] - cx2;
          v2f dy = py[j] - cy2;
          v2f dz = pz[j] - cz2;
          v2f t1 = dx * dx;
          v2f t2 = dy * dy;
          v2f t3 = dz * dz;
          v2f d  = (t1 + t2) + t3;         // ((dx^2+dy^2)+dz^2)
          v2f od = dist[j];
          v2f nd = (v2f){__builtin_fminf(od.x, d.x), __builtin_fminf(od.y, d.y)};
          dist[j] = nd;
          nb = fmaxf(fmaxf(nb, nd.x), nd.y);   // v_max3
        }
        ub = nb;
      }
      // f32 wave value max (3 instrs/stage)
      float bv = ub;
      DPP_MAXF0(DPP_ROW_SHR1,   bv);
      DPP_MAXF0(DPP_ROW_SHR2,   bv);
      DPP_MAXF0(DPP_ROW_SHR4,   bv);
      DPP_MAXF0(DPP_ROW_SHR8,   bv);
      DPP_MAXF0(DPP_ROW_BCAST15, bv);
      DPP_MAXF0(DPP_ROW_BCAST31, bv);
      float bmw = __int_as_float(
          __builtin_amdgcn_readlane(__float_as_int(bv), 63));
      // guarded locate: min ORIGINAL index among dist==bmw (bit-exact match)
      int mi = 0x7fffffff;
      if (ub == bmw){
#pragma unroll
        for (int j = 0; j < 8; ++j){
          if (dist[j].x == bmw){ int o = perm_reg[j] & 0xffff;         mi = o < mi ? o : mi; }
          if (dist[j].y == bmw){ int o = (perm_reg[j] >> 16) & 0xffff; mi = o < mi ? o : mi; }
        }
      }
      DPP_MINI(DPP_ROW_SHR1,   mi);
      DPP_MINI(DPP_ROW_SHR2,   mi);
      DPP_MINI(DPP_ROW_SHR4,   mi);
      DPP_MINI(DPP_ROW_SHR8,   mi);
      DPP_MINI(DPP_ROW_BCAST15, mi);
      DPP_MINI(DPP_ROW_BCAST31, mi);
      int miw = __builtin_amdgcn_readlane(mi, 63);
      key = ((unsigned long long)__float_as_uint(bmw) << 15)
          | (unsigned long long)(16384 - miw);
    }
    // publish wave key (cached when the wave skipped -- provably unchanged)
    const int par = s & 1;
    if (lane == 0) lslotK[par][wid] = key;
    __syncthreads();
    // cross-wave u64 reduce: 16 slots on lanes 0-15 of each row
    unsigned long long kk = lslotK[par][lane & 15];
    DPP_MAXK0(DPP_ROW_SHR1, kk);
    DPP_MAXK0(DPP_ROW_SHR2, kk);
    DPP_MAXK0(DPP_ROW_SHR4, kk);
    DPP_MAXK0(DPP_ROW_SHR8, kk);
    unsigned blo = (unsigned)__builtin_amdgcn_readlane((int)(unsigned)kk, 15);
    unsigned bhi = (unsigned)__builtin_amdgcn_readlane((int)(unsigned)(kk >> 32), 15);
    unsigned long long kmax = (((unsigned long long)bhi) << 32) | blo;
    int ufi = 16384 - (int)(kmax & 0x7FFFull);
    const float* cp = pb + (size_t)ufi*3;   // uniform -> s_load, L2-hot
    cx = cp[0]; cy = cp[1]; cz = cp[2];
  }
}

// ---------------------------------------------------------------------------
// Ball query: one wave per center. Ordered compaction of the first 32
// in-radius indices (ascending index order == jnp.sort-then-truncate).
// ---------------------------------------------------------------------------
__global__ __launch_bounds__(256) void ballq_kernel(const float* __restrict__ pos,
                                                    const float* __restrict__ centers,
                                                    int* __restrict__ idx){
#pragma clang fp contract(off)
  const float R2 = (float)(0.2*0.2);   // match Python double 0.2*0.2 -> f32
  int wid  = blockIdx.x*4 + (threadIdx.x >> 6);
  int lane = threadIdx.x & 63;
  int b = wid >> 10;                   // wid / S
  const float* pb = pos + (size_t)b * NPTS * 3;
  float cx = centers[wid*3+0], cy = centers[wid*3+1], cz = centers[wid*3+2];
  int* out = idx + wid*KNEI;
  int count = 0; int first = -1;
  for (int base = 0; base < NPTS; base += 64){
    int p = base + lane;
    float dx = pb[p*3+0]-cx, dy = pb[p*3+1]-cy, dz = pb[p*3+2]-cz;
    float t1 = dx*dx, t2 = dy*dy, t3 = dz*dz;
    float d = (t1 + t2) + t3;
    bool inr = d <= R2;
    unsigned long long mask = __ballot(inr);
    if (count == 0 && mask) first = base + __builtin_ctzll(mask);
    if (inr){
      int slot = count + __popcll(mask & ((1ull << lane) - 1ull));
      if (slot < KNEI) out[slot] = p;
    }
    count += __popcll(mask);
    if (count >= KNEI) break;
  }
  if (count < KNEI){
    for (int slot = count + lane; slot < KNEI; slot += 64) out[slot] = first;
  }
}

// ---------------------------------------------------------------------------
// GEMM1 sem: h1[m][0:64] = feat[b, idx[m], :] @ w(64x64) + bias.
// Block: 256 threads, 64-row tile. Also accumulates per-channel sum/sumsq.
// ---------------------------------------------------------------------------
__global__ __launch_bounds__(256) void gemm_sem1(const float* __restrict__ feat,
    const int* __restrict__ idx, const float* __restrict__ w,
    const float* __restrict__ bias, float* __restrict__ h1,
    float* __restrict__ stat){
  __shared__ float xs[64][68];
  __shared__ float wsh[64][64];
  const int tid = threadIdx.x;
  const int m0 = blockIdx.x * 64;
#pragma unroll
  for (int i = 0; i < 4; ++i){
    int q = tid + i*256;                 // 1024 quads of w (64x64)
    int r = q >> 4, c4 = q & 15;
    *(float4*)&wsh[r][c4*4] = *(const float4*)&w[r*64 + c4*4];
  }
#pragma unroll
  for (int i = 0; i < 4; ++i){
    int q = tid + i*256;                 // 1024 quads of x tile (64x64)
    int r = q >> 4, c4 = q & 15;
    int m = m0 + r;
    int nb = idx[m];
    int b = m >> 15;                     // m / (S*KNEI)
    const float* fr = feat + ((size_t)b*NPTS + nb)*64;
    *(float4*)&xs[r][c4*4] = *(const float4*)&fr[c4*4];
  }
  __syncthreads();
  const int g  = tid & 7;                // channel group: 8 channels
  const int rt = tid >> 3;               // 32 row-threads, 2 rows each
  const int r0 = rt * 2;
  float acc[2][8];
#pragma unroll
  for (int c = 0; c < 8; ++c){ float bb = bias[g*8+c]; acc[0][c] = bb; acc[1][c] = bb; }
  for (int k = 0; k < 64; ++k){
    float x0 = xs[r0][k], x1 = xs[r0+1][k];
    float4 wa = *(float4*)&wsh[k][g*8];
    float4 wb = *(float4*)&wsh[k][g*8+4];
    float wv[8] = {wa.x,wa.y,wa.z,wa.w,wb.x,wb.y,wb.z,wb.w};
#pragma unroll
    for (int c = 0; c < 8; ++c){ acc[0][c] += x0*wv[c]; acc[1][c] += x1*wv[c]; }
  }
#pragma unroll
  for (int r = 0; r < 2; ++r){
    float* dst = h1 + (size_t)(m0 + r0 + r)*64 + g*8;
    *(float4*)dst     = make_float4(acc[r][0],acc[r][1],acc[r][2],acc[r][3]);
    *(float4*)(dst+4) = make_float4(acc[r][4],acc[r][5],acc[r][6],acc[r][7]);
  }
  float ls[8], lq[8];
#pragma unroll
  for (int c = 0; c < 8; ++c){
    ls[c] = acc[0][c] + acc[1][c];
    lq[c] = acc[0][c]*acc[0][c] + acc[1][c]*acc[1][c];
  }
  __syncthreads();
  float* red  = &xs[0][0];
  float* redq = &wsh[0][0];
#pragma unroll
  for (int c = 0; c < 8; ++c){
    red[(g*8+c)*32 + rt]  = ls[c];
    redq[(g*8+c)*32 + rt] = lq[c];
  }
  __syncthreads();
  if (tid < 128){
    int c = tid & 63;
    const float* src = (tid < 64) ? red : redq;
    float a2 = 0.f;
    for (int i = 0; i < 32; ++i) a2 += src[c*32+i];
    atomicAdd(&stat[(tid < 64 ? 0 : 64) + c], a2);
  }
}

// ---------------------------------------------------------------------------
// GEMM2 fused (sem & geo layer 2): x = relu(a*hin+d) (folded BN1), 128 out
// channels. Does NOT materialize h2: BN2's scale a = gamma*rsqrt(var) with
// gamma==1 > 0, so max_k(a*h+d) == a*(max_k h)+d exactly (monotone affine);
// reduce max over k IN-BLOCK, emit 2x128 floats/block. Stats unchanged.
// ---------------------------------------------------------------------------
__global__ __launch_bounds__(256) void gemm2_fused(const float* __restrict__ hin,
    const float* __restrict__ abn, const float* __restrict__ dbn,
    const float* __restrict__ w, const float* __restrict__ bias,
    float* __restrict__ hmax, float* __restrict__ stat){
  __shared__ float xs[64][68];
  __shared__ float wsh[64][128];
  const int tid = threadIdx.x;
  const int m0 = blockIdx.x * 64;
#pragma unroll
  for (int i = 0; i < 8; ++i){
    int q = tid + i*256;                 // 2048 quads of w (64x128)
    int r = q >> 5, c4 = q & 31;
    *(float4*)&wsh[r][c4*4] = *(const float4*)&w[r*128 + c4*4];
  }
#pragma unroll
  for (int i = 0; i < 4; ++i){
    int q = tid + i*256;
    int r = q >> 4, c4 = q & 15;
    float4 v  = *(const float4*)&hin[(size_t)(m0+r)*64 + c4*4];
    float4 av = *(const float4*)&abn[c4*4];
    float4 dv = *(const float4*)&dbn[c4*4];
    v.x = fmaxf(v.x*av.x + dv.x, 0.f);
    v.y = fmaxf(v.y*av.y + dv.y, 0.f);
    v.z = fmaxf(v.z*av.z + dv.z, 0.f);
    v.w = fmaxf(v.w*av.w + dv.w, 0.f);
    *(float4*)&xs[r][c4*4] = v;
  }
  __syncthreads();
  const int g  = tid & 15;               // 16 groups x 8 ch = 128
  const int rt = tid >> 4;               // 16 row-threads x 4 rows = 64
  const int r0 = rt * 4;                 // rows r0..r0+3 all in group rt>>3
  float acc[4][8];
#pragma unroll
  for (int c = 0; c < 8; ++c){
    float bb = bias[g*8+c];
    acc[0][c]=bb; acc[1][c]=bb; acc[2][c]=bb; acc[3][c]=bb;
  }
  for (int k = 0; k < 64; ++k){
    float x0 = xs[r0][k], x1 = xs[r0+1][k], x2 = xs[r0+2][k], x3 = xs[r0+3][k];
    float4 wa = *(float4*)&wsh[k][g*8];
    float4 wb = *(float4*)&wsh[k][g*8+4];
    float wv[8] = {wa.x,wa.y,wa.z,wa.w,wb.x,wb.y,wb.z,wb.w};
#pragma unroll
    for (int c = 0; c < 8; ++c){
      acc[0][c] += x0*wv[c]; acc[1][c] += x1*wv[c];
      acc[2][c] += x2*wv[c]; acc[3][c] += x3*wv[c];
    }
  }
  float ls[8], lq[8], tmax[8];
#pragma unroll
  for (int c = 0; c < 8; ++c){
    ls[c] = acc[0][c]+acc[1][c]+acc[2][c]+acc[3][c];
    lq[c] = acc[0][c]*acc[0][c]+acc[1][c]*acc[1][c]+acc[2][c]*acc[2][c]+acc[3][c]*acc[3][c];
    tmax[c] = fmaxf(fmaxf(acc[0][c],acc[1][c]), fmaxf(acc[2][c],acc[3][c]));
  }
  __syncthreads();
  float* red  = &xs[0][0];               // 2048 sums + 2048 sumsq (<= 64*68)
  float* mred = &wsh[0][0];              // 16 x 128 per-thread maxes
#pragma unroll
  for (int c = 0; c < 8; ++c){
    red[(g*8+c)*16 + rt]        = ls[c];
    red[2048 + (g*8+c)*16 + rt] = lq[c];
    mred[rt*128 + g*8 + c]      = tmax[c];
  }
  __syncthreads();
  {
    int c = tid & 127;
    int isq = tid >> 7;
    float a2 = 0.f;
    for (int i = 0; i < 16; ++i) a2 += red[isq*2048 + c*16 + i];
    atomicAdd(&stat[isq*128 + c], a2);
  }
  {
    int og = tid >> 7;                   // 0..1 (k-group within block)
    int c  = tid & 127;
    float m = -3.4e38f;
#pragma unroll
    for (int i = 0; i < 8; ++i) m = fmaxf(m, mred[(og*8 + i)*128 + c]);
    hmax[(size_t)(blockIdx.x*2 + og)*128 + c] = m;
  }
}

// ---------------------------------------------------------------------------
// GEMM1 geo: x = [center(3) | grouped_pos(3)] (6 ch) @ w(6x64) + bias.
// ---------------------------------------------------------------------------
__global__ __launch_bounds__(256) void gemm_geo1(const float* __restrict__ pos,
    const float* __restrict__ centers, const int* __restrict__ idx,
    const float* __restrict__ w, const float* __restrict__ bias,
    float* __restrict__ hout, float* __restrict__ stat){
  __shared__ float xs[64][8];
  __shared__ float wsh[6][64];
  __shared__ float red[2048];
  __shared__ float redq[2048];
  const int tid = threadIdx.x;
  const int m0 = blockIdx.x * 64;
  for (int i = tid; i < 384; i += 256) wsh[i >> 6][i & 63] = w[i];
  if (tid < 64){
    int m = m0 + tid;
    int grp = m >> 5;                    // m / KNEI
    int b = m >> 15;
    int nb = idx[m];
    const float* cp = centers + (size_t)grp*3;
    const float* pp = pos + ((size_t)b*NPTS + nb)*3;
    xs[tid][0]=cp[0]; xs[tid][1]=cp[1]; xs[tid][2]=cp[2];
    xs[tid][3]=pp[0]; xs[tid][4]=pp[1]; xs[tid][5]=pp[2];
  }
  __syncthreads();
  const int g  = tid & 7;
  const int rt = tid >> 3;
  const int r0 = rt * 2;
  float acc[2][8];
#pragma unroll
  for (int c = 0; c < 8; ++c){ float bb = bias[g*8+c]; acc[0][c]=bb; acc[1][c]=bb; }
#pragma unroll
  for (int k = 0; k < 6; ++k){
    float x0 = xs[r0][k], x1 = xs[r0+1][k];
    float4 wa = *(float4*)&wsh[k][g*8];
    float4 wb = *(float4*)&wsh[k][g*8+4];
    float wv[8] = {wa.x,wa.y,wa.z,wa.w,wb.x,wb.y,wb.z,wb.w};
#pragma unroll
    for (int c = 0; c < 8; ++c){ acc[0][c] += x0*wv[c]; acc[1][c] += x1*wv[c]; }
  }
#pragma unroll
  for (int r = 0; r < 2; ++r){
    float* dst = hout + (size_t)(m0 + r0 + r)*64 + g*8;
    *(float4*)dst     = make_float4(acc[r][0],acc[r][1],acc[r][2],acc[r][3]);
    *(float4*)(dst+4) = make_float4(acc[r][4],acc[r][5],acc[r][6],acc[r][7]);
  }
  float ls[8], lq[8];
#pragma unroll
  for (int c = 0; c < 8; ++c){
    ls[c] = acc[0][c] + acc[1][c];
    lq[c] = acc[0][c]*acc[0][c] + acc[1][c]*acc[1][c];
  }
#pragma unroll
  for (int c = 0; c < 8; ++c){
    red[(g*8+c)*32 + rt]  = ls[c];
    redq[(g*8+c)*32 + rt] = lq[c];
  }
  __syncthreads();
  if (tid < 128){
    int c = tid & 63;
    const float* src = (tid < 64) ? red : redq;
    float a2 = 0.f;
    for (int i = 0; i < 32; ++i) a2 += src[c*32+i];
    atomicAdd(&stat[(tid < 64 ? 0 : 64) + c], a2);
  }
}

// ---------------------------------------------------------------------------
// BN finalize: fold stats into per-channel scale/shift a,d.
// ---------------------------------------------------------------------------
__global__ void bn_finalize(const float* __restrict__ stat,
                            const float* __restrict__ gam, const float* __restrict__ bet,
                            float* __restrict__ a, float* __restrict__ d, int C){
  int c = threadIdx.x;
  if (c >= C) return;
  const float invM = 1.0f / (float)MROWS;
  float mu  = stat[c] * invM;
  float ex2 = stat[C + c] * invM;
  float var = ex2 - mu*mu;
  float aa = gam[c] * rsqrtf(var + 1e-5f);
  a[c] = aa;
  d[c] = bet[c] - mu*aa;
}

// ---------------------------------------------------------------------------
// BN apply on pooled maxes: out[i] = relu(a[c]*hmax[i]+d[c]).
// Exact vs old (maxpool over a*h+d): a>0 makes the affine monotone, so the
// max commutes with it bit-exactly.
// ---------------------------------------------------------------------------
__global__ __launch_bounds__(256) void bnapply_kernel(const float* __restrict__ hmax,
    const float* __restrict__ abn, const float* __restrict__ dbn,
    float* __restrict__ out){
  int i = blockIdx.x*256 + threadIdx.x;
  int c = i & 127;
  out[i] = fmaxf(hmax[i]*abn[c] + dbn[c], 0.f);
}

__global__ void zero_kernel(float* __restrict__ p, int n){
  int i = blockIdx.x*blockDim.x + threadIdx.x;
  if (i < n) p[i] = 0.f;
}

extern "C" void kernel_launch(void* const* d_in, const int* in_sizes, int n_in,
                              void* d_out, int out_size, void* d_ws, size_t ws_size,
                              hipStream_t stream){
  const float* pos   = (const float*)d_in[0];
  const float* feat  = (const float*)d_in[1];
  const float* w_s1  = (const float*)d_in[2];
  const float* b_s1  = (const float*)d_in[3];
  const float* g_s1  = (const float*)d_in[4];
  const float* be_s1 = (const float*)d_in[5];
  const float* w_s2  = (const float*)d_in[6];
  const float* b_s2  = (const float*)d_in[7];
  const float* g_s2  = (const float*)d_in[8];
  const float* be_s2 = (const float*)d_in[9];
  const float* w_g1  = (const float*)d_in[10];
  const float* b_g1  = (const float*)d_in[11];
  const float* g_g1  = (const float*)d_in[12];
  const float* be_g1 = (const float*)d_in[13];
  const float* w_g2  = (const float*)d_in[14];
  const float* b_g2  = (const float*)d_in[15];
  const float* g_g2  = (const float*)d_in[16];
  const float* be_g2 = (const float*)d_in[17];
  float* outp = (float*)d_out;
  float* wsf  = (float*)d_ws;

  // workspace layout (floats):
  float* centers = wsf;                         // 8192*3 = 24576
  int*   idxp    = (int*)(wsf + 24576);         // 262144
  float* stats   = wsf + 24576 + 262144;        // 768
  float* bnad    = stats + 768;                 // 768
  float* h1      = wsf + 288256;                // 262144*64
  float* scratch = h1 + (size_t)MROWS*64;       // former h2 region (free)
  // scratch usage: fps sorted coords (393216 f), then hmax1/hmax2 (1M f each)
  float* sortbuf = scratch;
  float* hmax1   = scratch + 524288;
  float* hmax2   = scratch + 524288 + 1048576;

  float* st1 = stats;        // 64 sum + 64 sq
  float* st2 = stats + 128;  // 128 + 128
  float* st3 = stats + 384;  // 64 + 64
  float* st4 = stats + 512;  // 128 + 128
  float* a1 = bnad;        float* d1 = bnad + 64;
  float* a2 = bnad + 128;  float* d2 = bnad + 256;
  float* a3 = bnad + 384;  float* d3 = bnad + 448;
  float* a4 = bnad + 512;  float* d4 = bnad + 640;

  zero_kernel<<<3, 256, 0, stream>>>(stats, 768);
  fps_kernel<<<NB, 1024, 0, stream>>>(pos, centers, sortbuf);
  ballq_kernel<<<(NB*S)/4, 256, 0, stream>>>(pos, centers, idxp);

  // sem branch
  gemm_sem1<<<MROWS/64, 256, 0, stream>>>(feat, idxp, w_s1, b_s1, h1, st1);
  bn_finalize<<<1, 128, 0, stream>>>(st1, g_s1, be_s1, a1, d1, 64);
  gemm2_fused<<<MROWS/64, 256, 0, stream>>>(h1, a1, d1, w_s2, b_s2, hmax1, st2);
  bn_finalize<<<1, 128, 0, stream>>>(st2, g_s2, be_s2, a2, d2, 128);
  bnapply_kernel<<<(NB*S*128)/256, 256, 0, stream>>>(hmax1, a2, d2, outp);

  // geo branch (reuses h1)
  gemm_geo1<<<MROWS/64, 256, 0, stream>>>(pos, centers, idxp, w_g1, b_g1, h1, st3);
  bn_finalize<<<1, 128, 0, stream>>>(st3, g_g1, be_g1, a3, d3, 64);
  gemm2_fused<<<MROWS/64, 256, 0, stream>>>(h1, a3, d3, w_g2, b_g2, hmax2, st4);
  bn_finalize<<<1, 128, 0, stream>>>(st4, g_g2, be_g2, a4, d4, 128);
  bnapply_kernel<<<(NB*S*128)/256, 256, 0, stream>>>(hmax2, a4, d4, outp + (size_t)NB*S*128);
}

// Round 10
// 1660.844 us; speedup vs baseline: 1.4030x; 1.0307x over previous
//
#include <hip/hip_runtime.h>

#define NB 8
#define NPTS 16384
#define S 1024
#define KNEI 32
#define MROWS (NB*S*KNEI)   // 262144

typedef float v2f __attribute__((ext_vector_type(2)));

// Value-only f32 max combine via DPP, bound_ctrl=1 (invalid lanes read 0 --
// safe identity: all reduced values are >= 0).
#define DPP_MAXF0(CTRL, v) do {                                               \
    int _o = __builtin_amdgcn_update_dpp(0, __float_as_int(v),                \
                                         (CTRL), 0xF, 0xF, true);             \
    (v) = fmaxf((v), __int_as_float(_o));                                     \
  } while (0)

// i32 min combine via DPP, identity INT_MAX via the 'old' operand
// (bound_ctrl=false keeps old where the source lane is invalid).
#define DPP_MINI(CTRL, v) do {                                                \
    int _o = __builtin_amdgcn_update_dpp((int)0x7fffffff, (v),                \
                                         (CTRL), 0xF, 0xF, false);            \
    (v) = (_o < (v)) ? _o : (v);                                              \
  } while (0)

// u64 key max combine via DPP halves, bound_ctrl=1 (identity 0 always loses:
// every real key >= 1 because of the 16384-idx field). Used ONLY in the
// 4-stage cross-wave reduce (r15 showed it's too costly for in-wave use).
#define DPP_MAXK0(CTRL, k) do {                                               \
    int _olo = __builtin_amdgcn_update_dpp(0, (int)(unsigned)(k),             \
                                           (CTRL), 0xF, 0xF, true);           \
    int _ohi = __builtin_amdgcn_update_dpp(0, (int)(unsigned)((k) >> 32),     \
                                           (CTRL), 0xF, 0xF, true);           \
    unsigned long long _ok = (((unsigned long long)(unsigned)_ohi) << 32)     \
                           | (unsigned)_olo;                                  \
    if (_ok > (k)) (k) = _ok;                                                 \
  } while (0)

#define DPP_ROW_SHR1   0x111
#define DPP_ROW_SHR2   0x112
#define DPP_ROW_SHR4   0x114
#define DPP_ROW_SHR8   0x118
#define DPP_ROW_BCAST15 0x142
#define DPP_ROW_BCAST31 0x143

// ---------------------------------------------------------------------------
// FPS r18 = r17 (1143us measured: Morton box-skip + key-only wave caching +
// f32/i32 chains + one barrier) + SPECULATIVE COORD PREFETCH:
// after the barrier each lane reads its slot key and immediately issues the
// 3 coord loads for that slot's point -- the ~250cyc L2 latency overlaps the
// ~150cyc u64 cross-wave chain; the winner's coords are then selected with
// 3 readlanes from the uniform slot index (bit-copies of pb[ufi*3..], so
// bit-exact vs r17's serial uniform load).
// Exact-match discipline: contract off, ((dx^2+dy^2)+dz^2) order, key =
// dist_bits<<15 | (16384-orig_idx) == numpy first-occurrence argmax.
// ---------------------------------------------------------------------------
__global__ __launch_bounds__(1024, 4) void fps_kernel(const float* __restrict__ pos,
                                                      float* __restrict__ centers,
                                                      float* __restrict__ sbuf){
#pragma clang fp contract(off)
  __shared__ int hist[4096];
  __shared__ int ts[1024];
  __shared__ unsigned short perm[16384];
  __shared__ unsigned long long lslotK[2][16];
  const int b = blockIdx.x;
  const int t = threadIdx.x;
  const int wid = t >> 6, lane = t & 63;
  const float* pb = pos + (size_t)b * NPTS * 3;
  float* ssx = sbuf + (size_t)b * 3 * NPTS;
  float* ssy = ssx + NPTS;
  float* ssz = ssy + NPTS;
  const int p0 = t * 16;

  // ---- phase 0: load raw points, Morton cell ids ----
  float c[48];
  {
    const float4* src = (const float4*)(pb + (size_t)t*48);
#pragma unroll
    for (int q = 0; q < 12; ++q) *(float4*)&c[q*4] = src[q];
  }
  int cell[16];
#pragma unroll
  for (int j = 0; j < 16; ++j){
    float x = c[3*j], y = c[3*j+1], z = c[3*j+2];
    int ix = (int)(x * 16.f); ix = ix < 0 ? 0 : (ix > 15 ? 15 : ix);
    int iy = (int)(y * 16.f); iy = iy < 0 ? 0 : (iy > 15 ? 15 : iy);
    int iz = (int)(z * 16.f); iz = iz < 0 ? 0 : (iz > 15 ? 15 : iz);
    int m = 0;
#pragma unroll
    for (int k = 0; k < 4; ++k){
      m |= ((ix >> k) & 1) << (3*k + 2);
      m |= ((iy >> k) & 1) << (3*k + 1);
      m |= ((iz >> k) & 1) << (3*k + 0);
    }
    cell[j] = m;
  }
  // histogram
#pragma unroll
  for (int i = 0; i < 4; ++i) hist[t*4 + i] = 0;
  __syncthreads();
#pragma unroll
  for (int j = 0; j < 16; ++j) atomicAdd(&hist[cell[j]], 1);
  __syncthreads();
  // prefix sum: per-thread 4 cells -> Hillis-Steele over 1024 thread sums
  int h0 = hist[t*4], h1 = hist[t*4+1], h2v = hist[t*4+2];
  ts[t] = h0 + h1 + h2v + hist[t*4+3];
  __syncthreads();
  for (int off = 1; off < 1024; off <<= 1){
    int add = (t >= off) ? ts[t - off] : 0;
    __syncthreads();
    ts[t] += add;
    __syncthreads();
  }
  {
    int base = (t == 0) ? 0 : ts[t-1];
    hist[t*4]   = base;
    hist[t*4+1] = base + h0;
    hist[t*4+2] = base + h0 + h1;
    hist[t*4+3] = base + h0 + h1 + h2v;
  }
  __syncthreads();
  // scatter sorted coords to global scratch; permutation to LDS
#pragma unroll
  for (int j = 0; j < 16; ++j){
    int dst = atomicAdd(&hist[cell[j]], 1);
    ssx[dst] = c[3*j];
    ssy[dst] = c[3*j+1];
    ssz[dst] = c[3*j+2];
    perm[dst] = (unsigned short)(p0 + j);
  }
  __syncthreads();

  // ---- reload sorted points into registers; box; orig-idx pairs ----
  v2f px[8], py[8], pz[8], dist[8];
  int perm_reg[8];
#pragma unroll
  for (int g = 0; g < 4; ++g){
    float4 vx = *(const float4*)&ssx[p0 + g*4];
    float4 vy = *(const float4*)&ssy[p0 + g*4];
    float4 vz = *(const float4*)&ssz[p0 + g*4];
    px[g*2]   = (v2f){vx.x, vx.y}; px[g*2+1] = (v2f){vx.z, vx.w};
    py[g*2]   = (v2f){vy.x, vy.y}; py[g*2+1] = (v2f){vy.z, vy.w};
    pz[g*2]   = (v2f){vz.x, vz.y}; pz[g*2+1] = (v2f){vz.z, vz.w};
  }
#pragma unroll
  for (int j = 0; j < 8; ++j){
    perm_reg[j] = (int)perm[p0 + 2*j] | ((int)perm[p0 + 2*j + 1] << 16);
  }
  float bxl = 1e30f, bxh = -1e30f, byl = 1e30f, byh = -1e30f;
  float bzl = 1e30f, bzh = -1e30f;
#pragma unroll
  for (int j = 0; j < 8; ++j){
    asm volatile("" : "+v"(px[j]), "+v"(py[j]), "+v"(pz[j]), "+v"(perm_reg[j]));
    bxl = fminf(bxl, fminf(px[j].x, px[j].y));
    bxh = fmaxf(bxh, fmaxf(px[j].x, px[j].y));
    byl = fminf(byl, fminf(py[j].x, py[j].y));
    byh = fmaxf(byh, fmaxf(py[j].x, py[j].y));
    bzl = fminf(bzl, fminf(pz[j].x, pz[j].y));
    bzh = fmaxf(bzh, fmaxf(pz[j].x, pz[j].y));
    dist[j] = (v2f){1e10f, 1e10f};
  }
  float ub = 1e10f;
  unsigned long long key = 0;                  // cached wave-reduced key
  float cx = pb[0], cy = pb[1], cz = pb[2];    // far=0 initial centroid

  // ---- phase 1: the serial FPS loop ----
  for (int s = 0; s < S; ++s){
    if (t == 0){
      float* cd = centers + (size_t)(b*S + s)*3;
      cd[0] = cx; cd[1] = cy; cd[2] = cz;
    }
    // box skip test (conservative margin: provably no dist changes)
    float lx = fmaxf(fmaxf(bxl - cx, cx - bxh), 0.f);
    float ly = fmaxf(fmaxf(byl - cy, cy - byh), 0.f);
    float lz = fmaxf(fmaxf(bzl - cz, cz - bzh), 0.f);
    float lb2 = ((lx*lx + ly*ly) + lz*lz);
    bool act = !(lb2 * 0.99999f >= ub);
    unsigned long long am = __ballot((int)act);
    if (am){                               // wave-uniform branch
      if (act){
        v2f cx2 = (v2f){cx, cx}, cy2 = (v2f){cy, cy}, cz2 = (v2f){cz, cz};
        float nb = 0.0f;
#pragma unroll
        for (int j = 0; j < 8; ++j){
          v2f dx = px[j] - cx2;
          v2f dy = py[j] - cy2;
          v2f dz = pz[j] - cz2;
          v2f t1 = dx * dx;
          v2f t2 = dy * dy;
          v2f t3 = dz * dz;
          v2f d  = (t1 + t2) + t3;         // ((dx^2+dy^2)+dz^2)
          v2f od = dist[j];
          v2f nd = (v2f){__builtin_fminf(od.x, d.x), __builtin_fminf(od.y, d.y)};
          dist[j] = nd;
          nb = fmaxf(fmaxf(nb, nd.x), nd.y);   // v_max3
        }
        ub = nb;
      }
      // f32 wave value max (3 instrs/stage)
      float bv = ub;
      DPP_MAXF0(DPP_ROW_SHR1,   bv);
      DPP_MAXF0(DPP_ROW_SHR2,   bv);
      DPP_MAXF0(DPP_ROW_SHR4,   bv);
      DPP_MAXF0(DPP_ROW_SHR8,   bv);
      DPP_MAXF0(DPP_ROW_BCAST15, bv);
      DPP_MAXF0(DPP_ROW_BCAST31, bv);
      float bmw = __int_as_float(
          __builtin_amdgcn_readlane(__float_as_int(bv), 63));
      // guarded locate: min ORIGINAL index among dist==bmw (bit-exact match)
      int mi = 0x7fffffff;
      if (ub == bmw){
#pragma unroll
        for (int j = 0; j < 8; ++j){
          if (dist[j].x == bmw){ int o = perm_reg[j] & 0xffff;         mi = o < mi ? o : mi; }
          if (dist[j].y == bmw){ int o = (perm_reg[j] >> 16) & 0xffff; mi = o < mi ? o : mi; }
        }
      }
      DPP_MINI(DPP_ROW_SHR1,   mi);
      DPP_MINI(DPP_ROW_SHR2,   mi);
      DPP_MINI(DPP_ROW_SHR4,   mi);
      DPP_MINI(DPP_ROW_SHR8,   mi);
      DPP_MINI(DPP_ROW_BCAST15, mi);
      DPP_MINI(DPP_ROW_BCAST31, mi);
      int miw = __builtin_amdgcn_readlane(mi, 63);
      key = ((unsigned long long)__float_as_uint(bmw) << 15)
          | (unsigned long long)(16384 - miw);
    }
    // publish wave key (cached when the wave skipped -- provably unchanged)
    const int par = s & 1;
    if (lane == 0) lslotK[par][wid] = key;
    __syncthreads();
    // per-lane slot read + SPECULATIVE coord prefetch (overlaps the chain)
    unsigned long long kk = lslotK[par][lane & 15];
    int ufi_l = 16384 - (int)(kk & 0x7FFFull);
    const float* cpl = pb + (size_t)ufi_l*3;
    float wx = cpl[0], wy = cpl[1], wz = cpl[2];
    unsigned long long kko = kk;
    DPP_MAXK0(DPP_ROW_SHR1, kk);
    DPP_MAXK0(DPP_ROW_SHR2, kk);
    DPP_MAXK0(DPP_ROW_SHR4, kk);
    DPP_MAXK0(DPP_ROW_SHR8, kk);
    unsigned blo = (unsigned)__builtin_amdgcn_readlane((int)(unsigned)kk, 15);
    unsigned bhi = (unsigned)__builtin_amdgcn_readlane((int)(unsigned)(kk >> 32), 15);
    unsigned long long bkmax = (((unsigned long long)bhi) << 32) | blo;
    // winning slot: keys are unique (contain orig idx of disjoint point sets)
    unsigned m16 = (unsigned)__ballot((int)(kko == bkmax)) & 0xffffu;
    int sidx = (int)__builtin_ctz(m16);        // uniform (SGPR)
    cx = __int_as_float(__builtin_amdgcn_readlane(__float_as_int(wx), sidx));
    cy = __int_as_float(__builtin_amdgcn_readlane(__float_as_int(wy), sidx));
    cz = __int_as_float(__builtin_amdgcn_readlane(__float_as_int(wz), sidx));
  }
}

// ---------------------------------------------------------------------------
// Ball query (+ stats zeroing, absorbing the old zero_kernel launch).
// One wave per center; ordered compaction of the first 32 in-radius indices.
// ---------------------------------------------------------------------------
__global__ __launch_bounds__(256) void ballq_kernel(const float* __restrict__ pos,
                                                    const float* __restrict__ centers,
                                                    int* __restrict__ idx,
                                                    float* __restrict__ stats){
#pragma clang fp contract(off)
  if (blockIdx.x < 3) stats[blockIdx.x*256 + threadIdx.x] = 0.f;
  const float R2 = (float)(0.2*0.2);   // match Python double 0.2*0.2 -> f32
  int wid  = blockIdx.x*4 + (threadIdx.x >> 6);
  int lane = threadIdx.x & 63;
  int b = wid >> 10;                   // wid / S
  const float* pb = pos + (size_t)b * NPTS * 3;
  float cx = centers[wid*3+0], cy = centers[wid*3+1], cz = centers[wid*3+2];
  int* out = idx + wid*KNEI;
  int count = 0; int first = -1;
  for (int base = 0; base < NPTS; base += 64){
    int p = base + lane;
    float dx = pb[p*3+0]-cx, dy = pb[p*3+1]-cy, dz = pb[p*3+2]-cz;
    float t1 = dx*dx, t2 = dy*dy, t3 = dz*dz;
    float d = (t1 + t2) + t3;
    bool inr = d <= R2;
    unsigned long long mask = __ballot(inr);
    if (count == 0 && mask) first = base + __builtin_ctzll(mask);
    if (inr){
      int slot = count + __popcll(mask & ((1ull << lane) - 1ull));
      if (slot < KNEI) out[slot] = p;
    }
    count += __popcll(mask);
    if (count >= KNEI) break;
  }
  if (count < KNEI){
    for (int slot = count + lane; slot < KNEI; slot += 64) out[slot] = first;
  }
}

// ---------------------------------------------------------------------------
// GEMM1 both branches in ONE kernel (8192 blocks):
//  blocks [0,4096):   sem -- h1s[m] = feat[b, idx[m], :] @ w_s(64x64)+b_s
//  blocks [4096,8192): geo -- h1g[m] = [center|grouped_pos](6) @ w_g(6x64)+b_g
// Both accumulate per-channel sum/sumsq into their stat sets.
// ---------------------------------------------------------------------------
__global__ __launch_bounds__(256) void gemm1_both(const float* __restrict__ feat,
    const float* __restrict__ pos, const float* __restrict__ centers,
    const int* __restrict__ idx,
    const float* __restrict__ w_s, const float* __restrict__ b_s,
    float* __restrict__ h1s, float* __restrict__ st_s,
    const float* __restrict__ w_g, const float* __restrict__ b_g,
    float* __restrict__ h1g, float* __restrict__ st_g){
  __shared__ float smem[8448];           // union of both branch layouts
  const int tid = threadIdx.x;
  if (blockIdx.x < (MROWS/64)){
    // ------------------- sem branch -------------------
    float (*xs)[68]  = (float(*)[68])smem;          // 64x68
    float (*wsh)[64] = (float(*)[64])(smem + 4352); // 64x64
    const int m0 = blockIdx.x * 64;
#pragma unroll
    for (int i = 0; i < 4; ++i){
      int q = tid + i*256;
      int r = q >> 4, c4 = q & 15;
      *(float4*)&wsh[r][c4*4] = *(const float4*)&w_s[r*64 + c4*4];
    }
#pragma unroll
    for (int i = 0; i < 4; ++i){
      int q = tid + i*256;
      int r = q >> 4, c4 = q & 15;
      int m = m0 + r;
      int nb = idx[m];
      int b = m >> 15;
      const float* fr = feat + ((size_t)b*NPTS + nb)*64;
      *(float4*)&xs[r][c4*4] = *(const float4*)&fr[c4*4];
    }
    __syncthreads();
    const int g  = tid & 7;
    const int rt = tid >> 3;
    const int r0 = rt * 2;
    float acc[2][8];
#pragma unroll
    for (int c = 0; c < 8; ++c){ float bb = b_s[g*8+c]; acc[0][c] = bb; acc[1][c] = bb; }
    for (int k = 0; k < 64; ++k){
      float x0 = xs[r0][k], x1 = xs[r0+1][k];
      float4 wa = *(float4*)&wsh[k][g*8];
      float4 wb = *(float4*)&wsh[k][g*8+4];
      float wv[8] = {wa.x,wa.y,wa.z,wa.w,wb.x,wb.y,wb.z,wb.w};
#pragma unroll
      for (int c = 0; c < 8; ++c){ acc[0][c] += x0*wv[c]; acc[1][c] += x1*wv[c]; }
    }
#pragma unroll
    for (int r = 0; r < 2; ++r){
      float* dst = h1s + (size_t)(m0 + r0 + r)*64 + g*8;
      *(float4*)dst     = make_float4(acc[r][0],acc[r][1],acc[r][2],acc[r][3]);
      *(float4*)(dst+4) = make_float4(acc[r][4],acc[r][5],acc[r][6],acc[r][7]);
    }
    float ls[8], lq[8];
#pragma unroll
    for (int c = 0; c < 8; ++c){
      ls[c] = acc[0][c] + acc[1][c];
      lq[c] = acc[0][c]*acc[0][c] + acc[1][c]*acc[1][c];
    }
    __syncthreads();
    float* red  = smem;
    float* redq = smem + 4352;
#pragma unroll
    for (int c = 0; c < 8; ++c){
      red[(g*8+c)*32 + rt]  = ls[c];
      redq[(g*8+c)*32 + rt] = lq[c];
    }
    __syncthreads();
    if (tid < 128){
      int c = tid & 63;
      const float* src = (tid < 64) ? red : redq;
      float a2 = 0.f;
      for (int i = 0; i < 32; ++i) a2 += src[c*32+i];
      atomicAdd(&st_s[(tid < 64 ? 0 : 64) + c], a2);
    }
  } else {
    // ------------------- geo branch -------------------
    float (*xs)[8]   = (float(*)[8])smem;            // 64x8
    float (*wsh)[64] = (float(*)[64])(smem + 512);   // 6x64
    float* red  = smem + 896;                        // 2048
    float* redq = smem + 2944;                       // 2048
    const int m0 = (blockIdx.x - (MROWS/64)) * 64;
    for (int i = tid; i < 384; i += 256) wsh[i >> 6][i & 63] = w_g[i];
    if (tid < 64){
      int m = m0 + tid;
      int grp = m >> 5;
      int b = m >> 15;
      int nb = idx[m];
      const float* cp = centers + (size_t)grp*3;
      const float* pp = pos + ((size_t)b*NPTS + nb)*3;
      xs[tid][0]=cp[0]; xs[tid][1]=cp[1]; xs[tid][2]=cp[2];
      xs[tid][3]=pp[0]; xs[tid][4]=pp[1]; xs[tid][5]=pp[2];
    }
    __syncthreads();
    const int g  = tid & 7;
    const int rt = tid >> 3;
    const int r0 = rt * 2;
    float acc[2][8];
#pragma unroll
    for (int c = 0; c < 8; ++c){ float bb = b_g[g*8+c]; acc[0][c]=bb; acc[1][c]=bb; }
#pragma unroll
    for (int k = 0; k < 6; ++k){
      float x0 = xs[r0][k], x1 = xs[r0+1][k];
      float4 wa = *(float4*)&wsh[k][g*8];
      float4 wb = *(float4*)&wsh[k][g*8+4];
      float wv[8] = {wa.x,wa.y,wa.z,wa.w,wb.x,wb.y,wb.z,wb.w};
#pragma unroll
      for (int c = 0; c < 8; ++c){ acc[0][c] += x0*wv[c]; acc[1][c] += x1*wv[c]; }
    }
#pragma unroll
    for (int r = 0; r < 2; ++r){
      float* dst = h1g + (size_t)(m0 + r0 + r)*64 + g*8;
      *(float4*)dst     = make_float4(acc[r][0],acc[r][1],acc[r][2],acc[r][3]);
      *(float4*)(dst+4) = make_float4(acc[r][4],acc[r][5],acc[r][6],acc[r][7]);
    }
    float ls[8], lq[8];
#pragma unroll
    for (int c = 0; c < 8; ++c){
      ls[c] = acc[0][c] + acc[1][c];
      lq[c] = acc[0][c]*acc[0][c] + acc[1][c]*acc[1][c];
    }
#pragma unroll
    for (int c = 0; c < 8; ++c){
      red[(g*8+c)*32 + rt]  = ls[c];
      redq[(g*8+c)*32 + rt] = lq[c];
    }
    __syncthreads();
    if (tid < 128){
      int c = tid & 63;
      const float* src = (tid < 64) ? red : redq;
      float a2 = 0.f;
      for (int i = 0; i < 32; ++i) a2 += src[c*32+i];
      atomicAdd(&st_g[(tid < 64 ? 0 : 64) + c], a2);
    }
  }
}

// ---------------------------------------------------------------------------
// GEMM2 both branches in ONE kernel (8192 blocks), fused max-over-k.
// BN2 scale a = gamma*rsqrt(var) with gamma==1 > 0, so
// max_k(a*h+d) == a*(max_k h)+d exactly (monotone affine).
// ---------------------------------------------------------------------------
__global__ __launch_bounds__(256) void gemm2_both(
    const float* __restrict__ h1s, const float* __restrict__ a1,
    const float* __restrict__ d1, const float* __restrict__ w_s2,
    const float* __restrict__ b_s2, float* __restrict__ hmax1,
    float* __restrict__ st2,
    const float* __restrict__ h1g, const float* __restrict__ a3,
    const float* __restrict__ d3, const float* __restrict__ w_g2,
    const float* __restrict__ b_g2, float* __restrict__ hmax2,
    float* __restrict__ st4){
  __shared__ float xs[64][68];
  __shared__ float wsh[64][128];
  const int tid = threadIdx.x;
  const bool sem = blockIdx.x < (MROWS/64);
  const int bx = sem ? blockIdx.x : blockIdx.x - (MROWS/64);
  const float* hin  = sem ? h1s  : h1g;
  const float* abn  = sem ? a1   : a3;
  const float* dbn  = sem ? d1   : d3;
  const float* w    = sem ? w_s2 : w_g2;
  const float* bias = sem ? b_s2 : b_g2;
  float* hmax       = sem ? hmax1 : hmax2;
  float* stat       = sem ? st2  : st4;
  const int m0 = bx * 64;
#pragma unroll
  for (int i = 0; i < 8; ++i){
    int q = tid + i*256;                 // 2048 quads of w (64x128)
    int r = q >> 5, c4 = q & 31;
    *(float4*)&wsh[r][c4*4] = *(const float4*)&w[r*128 + c4*4];
  }
#pragma unroll
  for (int i = 0; i < 4; ++i){
    int q = tid + i*256;
    int r = q >> 4, c4 = q & 15;
    float4 v  = *(const float4*)&hin[(size_t)(m0+r)*64 + c4*4];
    float4 av = *(const float4*)&abn[c4*4];
    float4 dv = *(const float4*)&dbn[c4*4];
    v.x = fmaxf(v.x*av.x + dv.x, 0.f);
    v.y = fmaxf(v.y*av.y + dv.y, 0.f);
    v.z = fmaxf(v.z*av.z + dv.z, 0.f);
    v.w = fmaxf(v.w*av.w + dv.w, 0.f);
    *(float4*)&xs[r][c4*4] = v;
  }
  __syncthreads();
  const int g  = tid & 15;               // 16 groups x 8 ch = 128
  const int rt = tid >> 4;               // 16 row-threads x 4 rows = 64
  const int r0 = rt * 4;                 // rows r0..r0+3 all in group rt>>3
  float acc[4][8];
#pragma unroll
  for (int c = 0; c < 8; ++c){
    float bb = bias[g*8+c];
    acc[0][c]=bb; acc[1][c]=bb; acc[2][c]=bb; acc[3][c]=bb;
  }
  for (int k = 0; k < 64; ++k){
    float x0 = xs[r0][k], x1 = xs[r0+1][k], x2 = xs[r0+2][k], x3 = xs[r0+3][k];
    float4 wa = *(float4*)&wsh[k][g*8];
    float4 wb = *(float4*)&wsh[k][g*8+4];
    float wv[8] = {wa.x,wa.y,wa.z,wa.w,wb.x,wb.y,wb.z,wb.w};
#pragma unroll
    for (int c = 0; c < 8; ++c){
      acc[0][c] += x0*wv[c]; acc[1][c] += x1*wv[c];
      acc[2][c] += x2*wv[c]; acc[3][c] += x3*wv[c];
    }
  }
  float ls[8], lq[8], tmax[8];
#pragma unroll
  for (int c = 0; c < 8; ++c){
    ls[c] = acc[0][c]+acc[1][c]+acc[2][c]+acc[3][c];
    lq[c] = acc[0][c]*acc[0][c]+acc[1][c]*acc[1][c]+acc[2][c]*acc[2][c]+acc[3][c]*acc[3][c];
    tmax[c] = fmaxf(fmaxf(acc[0][c],acc[1][c]), fmaxf(acc[2][c],acc[3][c]));
  }
  __syncthreads();
  float* red  = &xs[0][0];               // 2048 sums + 2048 sumsq (<= 64*68)
  float* mred = &wsh[0][0];              // 16 x 128 per-thread maxes
#pragma unroll
  for (int c = 0; c < 8; ++c){
    red[(g*8+c)*16 + rt]        = ls[c];
    red[2048 + (g*8+c)*16 + rt] = lq[c];
    mred[rt*128 + g*8 + c]      = tmax[c];
  }
  __syncthreads();
  {
    int c = tid & 127;
    int isq = tid >> 7;
    float a2 = 0.f;
    for (int i = 0; i < 16; ++i) a2 += red[isq*2048 + c*16 + i];
    atomicAdd(&stat[isq*128 + c], a2);
  }
  {
    int og = tid >> 7;                   // 0..1 (k-group within block)
    int c  = tid & 127;
    float m = -3.4e38f;
#pragma unroll
    for (int i = 0; i < 8; ++i) m = fmaxf(m, mred[(og*8 + i)*128 + c]);
    hmax[(size_t)(bx*2 + og)*128 + c] = m;
  }
}

// ---------------------------------------------------------------------------
// BN finalize, two stat sets per launch (block 0 = A, block 1 = B).
// ---------------------------------------------------------------------------
__global__ void bn_finalize2(const float* __restrict__ stA,
    const float* __restrict__ gamA, const float* __restrict__ betA,
    float* __restrict__ aA, float* __restrict__ dA,
    const float* __restrict__ stB,
    const float* __restrict__ gamB, const float* __restrict__ betB,
    float* __restrict__ aB, float* __restrict__ dB, int C){
  int c = threadIdx.x;
  if (c >= C) return;
  const float* stat = blockIdx.x ? stB : stA;
  const float* gam  = blockIdx.x ? gamB : gamA;
  const float* bet  = blockIdx.x ? betB : betA;
  float* a = blockIdx.x ? aB : aA;
  float* d = blockIdx.x ? dB : dA;
  const float invM = 1.0f / (float)MROWS;
  float mu  = stat[c] * invM;
  float ex2 = stat[C + c] * invM;
  float var = ex2 - mu*mu;
  float aa = gam[c] * rsqrtf(var + 1e-5f);
  a[c] = aa;
  d[c] = bet[c] - mu*aa;
}

// ---------------------------------------------------------------------------
// BN apply on pooled maxes, both branches: out[i] = relu(a[c]*hmax[i]+d[c]).
// Exact: a>0 makes the affine monotone, so max commutes bit-exactly.
// ---------------------------------------------------------------------------
__global__ __launch_bounds__(256) void bnapply_both(const float* __restrict__ hmax1,
    const float* __restrict__ a2, const float* __restrict__ d2,
    const float* __restrict__ hmax2,
    const float* __restrict__ a4, const float* __restrict__ d4,
    float* __restrict__ out){
  const int half = NB*S*128;
  int i = blockIdx.x*256 + threadIdx.x;
  if (i < half){
    int c = i & 127;
    out[i] = fmaxf(hmax1[i]*a2[c] + d2[c], 0.f);
  } else {
    int j = i - half;
    int c = j & 127;
    out[i] = fmaxf(hmax2[j]*a4[c] + d4[c], 0.f);
  }
}

extern "C" void kernel_launch(void* const* d_in, const int* in_sizes, int n_in,
                              void* d_out, int out_size, void* d_ws, size_t ws_size,
                              hipStream_t stream){
  const float* pos   = (const float*)d_in[0];
  const float* feat  = (const float*)d_in[1];
  const float* w_s1  = (const float*)d_in[2];
  const float* b_s1  = (const float*)d_in[3];
  const float* g_s1  = (const float*)d_in[4];
  const float* be_s1 = (const float*)d_in[5];
  const float* w_s2  = (const float*)d_in[6];
  const float* b_s2  = (const float*)d_in[7];
  const float* g_s2  = (const float*)d_in[8];
  const float* be_s2 = (const float*)d_in[9];
  const float* w_g1  = (const float*)d_in[10];
  const float* b_g1  = (const float*)d_in[11];
  const float* g_g1  = (const float*)d_in[12];
  const float* be_g1 = (const float*)d_in[13];
  const float* w_g2  = (const float*)d_in[14];
  const float* b_g2  = (const float*)d_in[15];
  const float* g_g2  = (const float*)d_in[16];
  const float* be_g2 = (const float*)d_in[17];
  float* outp = (float*)d_out;
  float* wsf  = (float*)d_ws;

  // workspace layout (floats):
  float* centers = wsf;                          // 24576
  int*   idxp    = (int*)(wsf + 24576);          // 262144
  float* stats   = wsf + 24576 + 262144;         // 768
  float* bnad    = stats + 768;                  // 768
  float* h1s     = wsf + 288256;                 // MROWS*64 = 16777216
  float* h1g     = h1s + (size_t)MROWS*64;       // 16777216
  float* sortbuf = h1g + (size_t)MROWS*64;       // 393216
  float* hmax1   = sortbuf + 393216;             // 1048576
  float* hmax2   = hmax1 + 1048576;              // 1048576
  // total ~= 36.3M floats ~= 139 MiB (< previous 193 MiB usage)

  float* st1 = stats;        // 64 sum + 64 sq
  float* st2 = stats + 128;  // 128 + 128
  float* st3 = stats + 384;  // 64 + 64
  float* st4 = stats + 512;  // 128 + 128
  float* a1 = bnad;        float* d1 = bnad + 64;
  float* a2 = bnad + 128;  float* d2 = bnad + 256;
  float* a3 = bnad + 384;  float* d3 = bnad + 448;
  float* a4 = bnad + 512;  float* d4 = bnad + 640;

  fps_kernel<<<NB, 1024, 0, stream>>>(pos, centers, sortbuf);
  ballq_kernel<<<(NB*S)/4, 256, 0, stream>>>(pos, centers, idxp, stats);
  gemm1_both<<<2*(MROWS/64), 256, 0, stream>>>(feat, pos, centers, idxp,
      w_s1, b_s1, h1s, st1, w_g1, b_g1, h1g, st3);
  bn_finalize2<<<2, 128, 0, stream>>>(st1, g_s1, be_s1, a1, d1,
                                      st3, g_g1, be_g1, a3, d3, 64);
  gemm2_both<<<2*(MROWS/64), 256, 0, stream>>>(h1s, a1, d1, w_s2, b_s2, hmax1, st2,
                                               h1g, a3, d3, w_g2, b_g2, hmax2, st4);
  bn_finalize2<<<2, 128, 0, stream>>>(st2, g_s2, be_s2, a2, d2,
                                      st4, g_g2, be_g2, a4, d4, 128);
  bnapply_both<<<(2*NB*S*128)/256, 256, 0, stream>>>(hmax1, a2, d2,
                                                     hmax2, a4, d4, outp);
}